// Round 2
// baseline (3006.171 us; speedup 1.0000x reference)
//
#include <hip/hip_runtime.h>
#include <hip/hip_bf16.h>

// monotonic float<->uint key for atomicMax-based segment max
__device__ __forceinline__ unsigned int fkey(float f) {
    unsigned int b = __float_as_uint(f);
    return (b & 0x80000000u) ? ~b : (b | 0x80000000u);
}
__device__ __forceinline__ float unkey(unsigned int k) {
    unsigned int b = (k & 0x80000000u) ? (k ^ 0x80000000u) : ~k;
    return __uint_as_float(b);
}

// ---------------- generic node GEMM: out = act(in @ W + bias) ----------------
// in: f32 [n, FIN] row-major; W: f32 [FIN, FOUT] row-major; out: f32 [n, FOUT].
// Thread per node; COLS output columns per block-chunk (chunk = blockIdx.x / bpc).
template<int FIN, int FOUT, int COLS, int ACT>
__global__ __launch_bounds__(256) void gemm_k(const float* __restrict__ in,
                                              const float* __restrict__ W,
                                              const float* __restrict__ bias,
                                              float* __restrict__ out,
                                              int n, int bpc)
{
    int chunk = blockIdx.x / bpc;            // wave-uniform
    int nb = blockIdx.x - chunk * bpc;
    int node = nb * 256 + threadIdx.x;
    if (node >= n) return;
    const int c0 = chunk * COLS;

    float acc[COLS];
    if (bias) {
        #pragma unroll
        for (int c = 0; c < COLS; ++c) acc[c] = bias[c0 + c];
    } else {
        #pragma unroll
        for (int c = 0; c < COLS; ++c) acc[c] = 0.f;
    }

    const float* row = in + (size_t)node * FIN;
    #pragma unroll 1
    for (int k4 = 0; k4 < FIN; k4 += 4) {
        float4 v = *(const float4*)(row + k4);
        const float* wbase = W + (size_t)k4 * FOUT + c0;
        #pragma unroll
        for (int c = 0; c < COLS; ++c) {
            float a = acc[c];
            a = fmaf(v.x, wbase[0 * FOUT + c], a);
            a = fmaf(v.y, wbase[1 * FOUT + c], a);
            a = fmaf(v.z, wbase[2 * FOUT + c], a);
            a = fmaf(v.w, wbase[3 * FOUT + c], a);
            acc[c] = a;
        }
    }

    if (ACT == 1) {
        #pragma unroll
        for (int c = 0; c < COLS; ++c) acc[c] = fmaxf(acc[c], 0.f);
    }

    float* orow = out + (size_t)node * FOUT + c0;
    #pragma unroll
    for (int c4 = 0; c4 < COLS; c4 += 4) {
        float4 ov = make_float4(acc[c4], acc[c4 + 1], acc[c4 + 2], acc[c4 + 3]);
        *(float4*)(orow + c4) = ov;
    }
}

// ---------------- per-node attention dot products ----------------
// h: f32 [n, H*D]; asr/adr: f32 [H, D]; outputs: f32 [n, H]
template<int H, int D>
__global__ __launch_bounds__(256) void attn_dots_k(const float* __restrict__ h,
                                                   const float* __restrict__ asr,
                                                   const float* __restrict__ adr,
                                                   float* __restrict__ as_o,
                                                   float* __restrict__ ad_o, int n)
{
    int t = blockIdx.x * 256 + threadIdx.x;
    if (t >= n * H) return;
    int node = t / H, hd = t - node * H;
    const float* row = h + (size_t)node * (H * D) + hd * D;
    const float* av = asr + hd * D;
    const float* bv = adr + hd * D;
    float ds = 0.f, dd = 0.f;
    #pragma unroll 1
    for (int k4 = 0; k4 < D; k4 += 4) {
        float4 v = *(const float4*)(row + k4);
        ds = fmaf(v.x, av[k4], fmaf(v.y, av[k4 + 1], fmaf(v.z, av[k4 + 2], fmaf(v.w, av[k4 + 3], ds))));
        dd = fmaf(v.x, bv[k4], fmaf(v.y, bv[k4 + 1], fmaf(v.z, bv[k4 + 2], fmaf(v.w, bv[k4 + 3], dd))));
    }
    as_o[t] = ds;
    ad_o[t] = dd;
}

// ---------------- edge passes ----------------
template<int H>
__global__ __launch_bounds__(256) void edge_max_k(const int* __restrict__ ei,
                                                  const float* __restrict__ as_,
                                                  const float* __restrict__ ad_,
                                                  unsigned int* __restrict__ m, int E)
{
    int e = blockIdx.x * 256 + threadIdx.x;
    if (e >= E) return;
    int s = ei[e], d = ei[E + e];
    #pragma unroll
    for (int hh = 0; hh < H; ++hh) {
        float v = as_[s * H + hh] + ad_[d * H + hh];
        v = v > 0.f ? v : 0.2f * v;
        atomicMax(&m[d * H + hh], fkey(v));
    }
}

template<int H>
__global__ __launch_bounds__(256) void edge_sum_k(const int* __restrict__ ei,
                                                  const float* __restrict__ as_,
                                                  const float* __restrict__ ad_,
                                                  const unsigned int* __restrict__ m,
                                                  float* __restrict__ den, int E)
{
    int e = blockIdx.x * 256 + threadIdx.x;
    if (e >= E) return;
    int s = ei[e], d = ei[E + e];
    #pragma unroll
    for (int hh = 0; hh < H; ++hh) {
        float v = as_[s * H + hh] + ad_[d * H + hh];
        v = v > 0.f ? v : 0.2f * v;
        float mf = unkey(m[d * H + hh]);
        atomicAdd(&den[d * H + hh], __expf(v - mf));
    }
}

// wave-cooperative aggregation: FEAT/2 lanes per edge, float2 per lane
template<int FEAT, int H>
__global__ __launch_bounds__(256) void edge_agg_k(const int* __restrict__ ei,
                                                  const float* __restrict__ as_,
                                                  const float* __restrict__ ad_,
                                                  const unsigned int* __restrict__ m,
                                                  const float* __restrict__ den,
                                                  const float* __restrict__ h,
                                                  float* __restrict__ agg, int E)
{
    constexpr int LPE = FEAT / 2;
    constexpr int EPB = 256 / LPE;
    constexpr int D = FEAT / H;
    int e = blockIdx.x * EPB + threadIdx.x / LPE;
    if (e >= E) return;
    int lane = threadIdx.x & (LPE - 1);
    int f = 2 * lane;
    int head = f / D;
    int s = ei[e], d = ei[E + e];
    float v = as_[s * H + head] + ad_[d * H + head];
    v = v > 0.f ? v : 0.2f * v;
    float mf = unkey(m[d * H + head]);
    float alpha = __expf(v - mf) / (den[d * H + head] + 1e-16f);
    float2 hv = *(const float2*)(h + (size_t)s * FEAT + f);
    atomicAdd(&agg[(size_t)d * FEAT + f],     hv.x * alpha);
    atomicAdd(&agg[(size_t)d * FEAT + f + 1], hv.y * alpha);
}

// ---------------- epilogues ----------------
// out = act(agg + bias), 4 elems/thread (safe in-place: same-index read/write)
template<int F, int ACT>
__global__ __launch_bounds__(256) void bias_act_k(const float* __restrict__ agg,
                                                  const float* __restrict__ bf,
                                                  float* __restrict__ out, int n)
{
    int t = blockIdx.x * 256 + threadIdx.x;
    int i4 = t * 4;
    if (i4 >= n * F) return;
    float4 a = *(const float4*)(agg + i4);
    int c = i4 & (F - 1);
    a.x += bf[c]; a.y += bf[c + 1]; a.z += bf[c + 2]; a.w += bf[c + 3];
    if (ACT == 1) {
        a.x = fmaxf(a.x, 0.f); a.y = fmaxf(a.y, 0.f);
        a.z = fmaxf(a.z, 0.f); a.w = fmaxf(a.w, 0.f);
    }
    *(float4*)(out + i4) = a;
}

// z = mu + eps * exp(0.5 * clip(logvar, -10, 10))
__global__ __launch_bounds__(256) void z_k(const float* __restrict__ mu,
                                           const float* __restrict__ lv,
                                           const float* __restrict__ eps,
                                           float* __restrict__ z, int total)
{
    int t = blockIdx.x * 256 + threadIdx.x;
    if (t >= total) return;
    float l = fminf(fmaxf(lv[t], -10.f), 10.f);
    z[t] = fmaf(eps[t], __expf(0.5f * l), mu[t]);
}

// ---------------- launch ----------------
extern "C" void kernel_launch(void* const* d_in, const int* in_sizes, int n_in,
                              void* d_out, int out_size, void* d_ws, size_t ws_size,
                              hipStream_t stream)
{
    const int n = in_sizes[0] / 128;     // N nodes
    const int E = in_sizes[1] / 2;       // edges

    const float* x   = (const float*)d_in[0];
    const int*   ei  = (const int*)d_in[1];
    const float* eps = (const float*)d_in[3];
    const float* W1  = (const float*)d_in[4];
    const float* as1w= (const float*)d_in[5];
    const float* ad1w= (const float*)d_in[6];
    const float* b1  = (const float*)d_in[7];
    const float* W2  = (const float*)d_in[8];
    const float* as2w= (const float*)d_in[9];
    const float* ad2w= (const float*)d_in[10];
    const float* b2  = (const float*)d_in[11];
    const float* fc1w= (const float*)d_in[12];
    const float* fc1b= (const float*)d_in[13];
    const float* muw = (const float*)d_in[14];
    const float* mub = (const float*)d_in[15];
    const float* lvw = (const float*)d_in[16];
    const float* lvb = (const float*)d_in[17];
    const float* fc3w= (const float*)d_in[18];
    const float* fc3b= (const float*)d_in[19];
    const float* fc4w= (const float*)d_in[20];
    const float* fc4b= (const float*)d_in[21];

    char* ws = (char*)d_ws;

    // workspace layout (bytes); atomic-scratch regions first so one memset covers them
    size_t oAgg1 = 0;                               // f32 [n,128] (hl2 applied in-place)
    size_t oAgg2 = oAgg1 + (size_t)n * 128 * 4;     // f32 [n,64]
    size_t oM1   = oAgg2 + (size_t)n * 64 * 4;      // u32 [n,2]
    size_t oD1   = oM1   + (size_t)n * 2 * 4;       // f32 [n,2]
    size_t oM2   = oD1   + (size_t)n * 2 * 4;       // u32 [n]
    size_t oD2   = oM2   + (size_t)n * 4;           // f32 [n]
    size_t zEnd  = oD2   + (size_t)n * 4;
    size_t oH1   = zEnd;                            // f32 [n,128] (h1; reused: h1v, h3)
    size_t oH2   = oH1   + (size_t)n * 128 * 4;     // f32 [n,64]  (h2; reused: zb)
    size_t oAS1  = oH2   + (size_t)n * 64 * 4;
    size_t oAD1  = oAS1  + (size_t)n * 2 * 4;
    size_t oAS2  = oAD1  + (size_t)n * 2 * 4;
    size_t oAD2  = oAS2  + (size_t)n * 4;

    float* agg1 = (float*)(ws + oAgg1);
    float* agg2 = (float*)(ws + oAgg2);
    unsigned int* m1 = (unsigned int*)(ws + oM1);
    float* den1 = (float*)(ws + oD1);
    unsigned int* m2 = (unsigned int*)(ws + oM2);
    float* den2 = (float*)(ws + oD2);
    float* h1   = (float*)(ws + oH1);
    float* h2   = (float*)(ws + oH2);
    float* as1  = (float*)(ws + oAS1);
    float* ad1  = (float*)(ws + oAD1);
    float* as2  = (float*)(ws + oAS2);
    float* ad2  = (float*)(ws + oAD2);
    float* hl2  = agg1;   // in-place bias+relu over agg1
    float* h1v  = h1;     // reuse
    float* h3   = h1;     // reuse
    float* zb   = h2;     // reuse

    float* out     = (float*)d_out;
    float* o_recon = out;
    float* o_mu    = out + (size_t)n * 64;
    float* o_lv    = out + (size_t)n * 80;
    float* o_gat   = out + (size_t)n * 96;

    const int bpc = (n + 255) / 256;
    const int ebl = (E + 255) / 256;

    // zero the atomic scratch (agg1, agg2, m1, den1, m2, den2)
    hipMemsetAsync(ws, 0, zEnd, stream);

    // --- GAT layer 1 ---
    gemm_k<128, 128, 32, 0><<<bpc * 4, 256, 0, stream>>>(x, W1, nullptr, h1, n, bpc);
    attn_dots_k<2, 64><<<(n * 2 + 255) / 256, 256, 0, stream>>>(h1, as1w, ad1w, as1, ad1, n);
    edge_max_k<2><<<ebl, 256, 0, stream>>>(ei, as1, ad1, m1, E);
    edge_sum_k<2><<<ebl, 256, 0, stream>>>(ei, as1, ad1, m1, den1, E);
    edge_agg_k<128, 2><<<(E + 3) / 4, 256, 0, stream>>>(ei, as1, ad1, m1, den1, h1, agg1, E);
    bias_act_k<128, 1><<<((size_t)n * 128 / 4 + 255) / 256, 256, 0, stream>>>(agg1, b1, hl2, n);

    // --- GAT layer 2 ---
    gemm_k<128, 64, 32, 0><<<bpc * 2, 256, 0, stream>>>(hl2, W2, nullptr, h2, n, bpc);
    attn_dots_k<1, 64><<<(n + 255) / 256, 256, 0, stream>>>(h2, as2w, ad2w, as2, ad2, n);
    edge_max_k<1><<<ebl, 256, 0, stream>>>(ei, as2, ad2, m2, E);
    edge_sum_k<1><<<ebl, 256, 0, stream>>>(ei, as2, ad2, m2, den2, E);
    edge_agg_k<64, 1><<<(E + 7) / 8, 256, 0, stream>>>(ei, as2, ad2, m2, den2, h2, agg2, E);
    bias_act_k<64, 0><<<((size_t)n * 64 / 4 + 255) / 256, 256, 0, stream>>>(agg2, b2, o_gat, n);

    // --- VAE ---
    gemm_k<64, 128, 32, 1><<<bpc * 4, 256, 0, stream>>>(o_gat, fc1w, fc1b, h1v, n, bpc);
    gemm_k<128, 16, 16, 0><<<bpc, 256, 0, stream>>>(h1v, muw, mub, o_mu, n, bpc);
    gemm_k<128, 16, 16, 0><<<bpc, 256, 0, stream>>>(h1v, lvw, lvb, o_lv, n, bpc);
    z_k<<<(n * 16 + 255) / 256, 256, 0, stream>>>(o_mu, o_lv, eps, zb, n * 16);
    gemm_k<16, 128, 32, 1><<<bpc * 4, 256, 0, stream>>>(zb, fc3w, fc3b, h3, n, bpc);
    gemm_k<128, 64, 32, 0><<<bpc * 2, 256, 0, stream>>>(h3, fc4w, fc4b, o_recon, n, bpc);
}

// Round 3
// 1098.491 us; speedup vs baseline: 2.7366x; 2.7366x over previous
//
#include <hip/hip_runtime.h>
#include <hip/hip_bf16.h>

// ---------------- generic node GEMM: out = act(in @ W + bias) ----------------
template<int FIN, int FOUT, int COLS, int ACT>
__global__ __launch_bounds__(256) void gemm_k(const float* __restrict__ in,
                                              const float* __restrict__ W,
                                              const float* __restrict__ bias,
                                              float* __restrict__ out,
                                              int n, int bpc)
{
    int chunk = blockIdx.x / bpc;            // wave-uniform
    int nb = blockIdx.x - chunk * bpc;
    int node = nb * 256 + threadIdx.x;
    if (node >= n) return;
    const int c0 = chunk * COLS;

    float acc[COLS];
    if (bias) {
        #pragma unroll
        for (int c = 0; c < COLS; ++c) acc[c] = bias[c0 + c];
    } else {
        #pragma unroll
        for (int c = 0; c < COLS; ++c) acc[c] = 0.f;
    }

    const float* row = in + (size_t)node * FIN;
    #pragma unroll 1
    for (int k4 = 0; k4 < FIN; k4 += 4) {
        float4 v = *(const float4*)(row + k4);
        const float* wbase = W + (size_t)k4 * FOUT + c0;
        #pragma unroll
        for (int c = 0; c < COLS; ++c) {
            float a = acc[c];
            a = fmaf(v.x, wbase[0 * FOUT + c], a);
            a = fmaf(v.y, wbase[1 * FOUT + c], a);
            a = fmaf(v.z, wbase[2 * FOUT + c], a);
            a = fmaf(v.w, wbase[3 * FOUT + c], a);
            acc[c] = a;
        }
    }

    if (ACT == 1) {
        #pragma unroll
        for (int c = 0; c < COLS; ++c) acc[c] = fmaxf(acc[c], 0.f);
    }

    float* orow = out + (size_t)node * FOUT + c0;
    #pragma unroll
    for (int c4 = 0; c4 < COLS; c4 += 4) {
        float4 ov = make_float4(acc[c4], acc[c4 + 1], acc[c4 + 2], acc[c4 + 3]);
        *(float4*)(orow + c4) = ov;
    }
}

// ---------------- per-node attention dot products ----------------
template<int H, int D>
__global__ __launch_bounds__(256) void attn_dots_k(const float* __restrict__ h,
                                                   const float* __restrict__ asr,
                                                   const float* __restrict__ adr,
                                                   float* __restrict__ as_o,
                                                   float* __restrict__ ad_o, int n)
{
    int t = blockIdx.x * 256 + threadIdx.x;
    if (t >= n * H) return;
    int node = t / H, hd = t - node * H;
    const float* row = h + (size_t)node * (H * D) + hd * D;
    const float* av = asr + hd * D;
    const float* bv = adr + hd * D;
    float ds = 0.f, dd = 0.f;
    #pragma unroll 1
    for (int k4 = 0; k4 < D; k4 += 4) {
        float4 v = *(const float4*)(row + k4);
        ds = fmaf(v.x, av[k4], fmaf(v.y, av[k4 + 1], fmaf(v.z, av[k4 + 2], fmaf(v.w, av[k4 + 3], ds))));
        dd = fmaf(v.x, bv[k4], fmaf(v.y, bv[k4 + 1], fmaf(v.z, bv[k4 + 2], fmaf(v.w, bv[k4 + 3], dd))));
    }
    as_o[t] = ds;
    ad_o[t] = dd;
}

// ---------------- CSR build ----------------
__global__ __launch_bounds__(256) void count_k(const int* __restrict__ ei, int* __restrict__ deg, int E)
{
    int e = blockIdx.x * 256 + threadIdx.x;
    if (e >= E) return;
    atomicAdd(&deg[ei[E + e]], 1);
}

// per-block inclusive scan (Hillis-Steele in LDS), block totals to bsum
__global__ __launch_bounds__(256) void scanA_k(const int* __restrict__ deg, int* __restrict__ incl,
                                               int* __restrict__ bsum, int n)
{
    __shared__ int sh[256];
    int i = blockIdx.x * 256 + threadIdx.x;
    int v = (i < n) ? deg[i] : 0;
    sh[threadIdx.x] = v;
    __syncthreads();
    #pragma unroll
    for (int o = 1; o < 256; o <<= 1) {
        int t = (threadIdx.x >= o) ? sh[threadIdx.x - o] : 0;
        __syncthreads();
        sh[threadIdx.x] += t;
        __syncthreads();
    }
    if (i < n) incl[i] = sh[threadIdx.x];
    if (threadIdx.x == 255) bsum[blockIdx.x] = sh[255];
}

// single-block exclusive scan of block sums (nb <= 512)
__global__ __launch_bounds__(512) void scanB_k(int* __restrict__ bsum, int nb)
{
    __shared__ int sh[512];
    int v = (threadIdx.x < nb) ? bsum[threadIdx.x] : 0;
    sh[threadIdx.x] = v;
    __syncthreads();
    #pragma unroll
    for (int o = 1; o < 512; o <<= 1) {
        int t = (threadIdx.x >= o) ? sh[threadIdx.x - o] : 0;
        __syncthreads();
        sh[threadIdx.x] += t;
        __syncthreads();
    }
    if (threadIdx.x < nb) bsum[threadIdx.x] = sh[threadIdx.x] - v;   // exclusive
}

// off[i] = exclusive prefix; cursor[i] = off[i]; off[n] = E
__global__ __launch_bounds__(256) void scanC_k(const int* __restrict__ deg, const int* __restrict__ incl,
                                               const int* __restrict__ bsum, int* __restrict__ off,
                                               int* __restrict__ cursor, int n, int E)
{
    int i = blockIdx.x * 256 + threadIdx.x;
    if (i >= n) return;
    int v = incl[i] - deg[i] + bsum[i >> 8];
    off[i] = v;
    cursor[i] = v;
    if (i == 0) off[n] = E;
}

__global__ __launch_bounds__(256) void scatter_k(const int* __restrict__ ei, int* __restrict__ cursor,
                                                 int* __restrict__ csr_src, int E)
{
    int e = blockIdx.x * 256 + threadIdx.x;
    if (e >= E) return;
    int s = ei[e], d = ei[E + e];
    int pos = atomicAdd(&cursor[d], 1);
    csr_src[pos] = s;
}

// ---------------- fused per-dst softmax + aggregate (wave-per-dst, no atomics) ----------------
// out[d] = act( sum_e alpha_e * h[src_e] + bias )
template<int FEAT, int H, int ACT>
__global__ __launch_bounds__(256) void gat_agg_k(const int* __restrict__ csr_src,
                                                 const int* __restrict__ off,
                                                 const float* __restrict__ as_,
                                                 const float* __restrict__ ad_,
                                                 const float* __restrict__ h,
                                                 const float* __restrict__ bias,
                                                 float* __restrict__ out, int n)
{
    constexpr int FPL = FEAT / 64;     // floats per lane (2 for 128, 1 for 64)
    constexpr int D = FEAT / H;
    int wid = (blockIdx.x * 256 + threadIdx.x) >> 6;
    if (wid >= n) return;
    const int lane = threadIdx.x & 63;
    const int d = wid;
    const int start = off[d], end = off[d + 1];

    float adv[H];
    #pragma unroll
    for (int hh = 0; hh < H; ++hh) adv[hh] = ad_[d * H + hh];

    // pass 1a: segment max per head
    float m[H];
    #pragma unroll
    for (int hh = 0; hh < H; ++hh) m[hh] = -3.4e38f;
    for (int j = start + lane; j < end; j += 64) {
        int s = csr_src[j];
        #pragma unroll
        for (int hh = 0; hh < H; ++hh) {
            float v = as_[s * H + hh] + adv[hh];
            v = v > 0.f ? v : 0.2f * v;
            m[hh] = fmaxf(m[hh], v);
        }
    }
    #pragma unroll
    for (int hh = 0; hh < H; ++hh)
        for (int o = 32; o > 0; o >>= 1)
            m[hh] = fmaxf(m[hh], __shfl_xor(m[hh], o, 64));

    // pass 1b: denom per head
    float den[H];
    #pragma unroll
    for (int hh = 0; hh < H; ++hh) den[hh] = 0.f;
    for (int j = start + lane; j < end; j += 64) {
        int s = csr_src[j];
        #pragma unroll
        for (int hh = 0; hh < H; ++hh) {
            float v = as_[s * H + hh] + adv[hh];
            v = v > 0.f ? v : 0.2f * v;
            den[hh] += __expf(v - m[hh]);
        }
    }
    #pragma unroll
    for (int hh = 0; hh < H; ++hh)
        for (int o = 32; o > 0; o >>= 1)
            den[hh] += __shfl_xor(den[hh], o, 64);

    // pass 2: weighted accumulate (serial over edges, lanes on features, 2-way unroll)
    const int myhead = (lane * FPL) / D;
    const float mh = m[myhead];
    const float inv = 1.f / (den[myhead] + 1e-16f);
    const float adm = adv[myhead];
    float acc[FPL];
    #pragma unroll
    for (int k = 0; k < FPL; ++k) acc[k] = 0.f;

    int j = start;
    for (; j + 1 < end; j += 2) {
        int s0 = csr_src[j], s1 = csr_src[j + 1];
        float v0 = as_[s0 * H + myhead] + adm; v0 = v0 > 0.f ? v0 : 0.2f * v0;
        float v1 = as_[s1 * H + myhead] + adm; v1 = v1 > 0.f ? v1 : 0.2f * v1;
        float a0 = __expf(v0 - mh) * inv;
        float a1 = __expf(v1 - mh) * inv;
        const float* r0 = h + (size_t)s0 * FEAT + lane * FPL;
        const float* r1 = h + (size_t)s1 * FEAT + lane * FPL;
        if constexpr (FPL == 2) {
            float2 x0 = *(const float2*)r0;
            float2 x1 = *(const float2*)r1;
            acc[0] = fmaf(x0.x, a0, fmaf(x1.x, a1, acc[0]));
            acc[1] = fmaf(x0.y, a0, fmaf(x1.y, a1, acc[1]));
        } else {
            acc[0] = fmaf(r0[0], a0, fmaf(r1[0], a1, acc[0]));
        }
    }
    for (; j < end; ++j) {
        int s0 = csr_src[j];
        float v0 = as_[s0 * H + myhead] + adm; v0 = v0 > 0.f ? v0 : 0.2f * v0;
        float a0 = __expf(v0 - mh) * inv;
        const float* r0 = h + (size_t)s0 * FEAT + lane * FPL;
        if constexpr (FPL == 2) {
            float2 x0 = *(const float2*)r0;
            acc[0] = fmaf(x0.x, a0, acc[0]);
            acc[1] = fmaf(x0.y, a0, acc[1]);
        } else {
            acc[0] = fmaf(r0[0], a0, acc[0]);
        }
    }

    // epilogue: bias (+relu), direct write
    #pragma unroll
    for (int k = 0; k < FPL; ++k) {
        float o = acc[k] + bias[lane * FPL + k];
        if (ACT == 1) o = fmaxf(o, 0.f);
        out[(size_t)d * FEAT + lane * FPL + k] = o;
    }
}

// z = mu + eps * exp(0.5 * clip(logvar, -10, 10))
__global__ __launch_bounds__(256) void z_k(const float* __restrict__ mu,
                                           const float* __restrict__ lv,
                                           const float* __restrict__ eps,
                                           float* __restrict__ z, int total)
{
    int t = blockIdx.x * 256 + threadIdx.x;
    if (t >= total) return;
    float l = fminf(fmaxf(lv[t], -10.f), 10.f);
    z[t] = fmaf(eps[t], __expf(0.5f * l), mu[t]);
}

// ---------------- launch ----------------
extern "C" void kernel_launch(void* const* d_in, const int* in_sizes, int n_in,
                              void* d_out, int out_size, void* d_ws, size_t ws_size,
                              hipStream_t stream)
{
    const int n = in_sizes[0] / 128;     // N nodes
    const int E = in_sizes[1] / 2;       // edges

    const float* x   = (const float*)d_in[0];
    const int*   ei  = (const int*)d_in[1];
    const float* eps = (const float*)d_in[3];
    const float* W1  = (const float*)d_in[4];
    const float* as1w= (const float*)d_in[5];
    const float* ad1w= (const float*)d_in[6];
    const float* b1  = (const float*)d_in[7];
    const float* W2  = (const float*)d_in[8];
    const float* as2w= (const float*)d_in[9];
    const float* ad2w= (const float*)d_in[10];
    const float* b2  = (const float*)d_in[11];
    const float* fc1w= (const float*)d_in[12];
    const float* fc1b= (const float*)d_in[13];
    const float* muw = (const float*)d_in[14];
    const float* mub = (const float*)d_in[15];
    const float* lvw = (const float*)d_in[16];
    const float* lvb = (const float*)d_in[17];
    const float* fc3w= (const float*)d_in[18];
    const float* fc3b= (const float*)d_in[19];
    const float* fc4w= (const float*)d_in[20];
    const float* fc4b= (const float*)d_in[21];

    char* ws = (char*)d_ws;

    // workspace layout (bytes)
    size_t oDeg   = 0;                                // int [n]  (memset each call)
    size_t oOff   = oDeg  + (size_t)n * 4;            // int [n+1]
    size_t oIncl  = oOff  + (size_t)(n + 1) * 4;      // int [n]
    size_t oCur   = oIncl + (size_t)n * 4;            // int [n]
    size_t oBsum  = oCur  + (size_t)n * 4;            // int [512]
    size_t oCsr   = oBsum + 512 * 4;                  // int [E]
    size_t oH1    = oCsr  + (size_t)E * 4;            // f32 [n,128] (reused: h1v, h3)
    size_t oHl2   = oH1   + (size_t)n * 128 * 4;      // f32 [n,128]
    size_t oH2    = oHl2  + (size_t)n * 128 * 4;      // f32 [n,64]  (reused: zb)
    size_t oAS1   = oH2   + (size_t)n * 64 * 4;
    size_t oAD1   = oAS1  + (size_t)n * 2 * 4;
    size_t oAS2   = oAD1  + (size_t)n * 2 * 4;
    size_t oAD2   = oAS2  + (size_t)n * 4;

    int* deg    = (int*)(ws + oDeg);
    int* off    = (int*)(ws + oOff);
    int* incl   = (int*)(ws + oIncl);
    int* cursor = (int*)(ws + oCur);
    int* bsum   = (int*)(ws + oBsum);
    int* csr    = (int*)(ws + oCsr);
    float* h1   = (float*)(ws + oH1);
    float* hl2  = (float*)(ws + oHl2);
    float* h2   = (float*)(ws + oH2);
    float* as1  = (float*)(ws + oAS1);
    float* ad1  = (float*)(ws + oAD1);
    float* as2  = (float*)(ws + oAS2);
    float* ad2  = (float*)(ws + oAD2);
    float* h1v  = h1;     // reuse
    float* h3   = h1;     // reuse
    float* zb   = h2;     // reuse

    float* out     = (float*)d_out;
    float* o_recon = out;
    float* o_mu    = out + (size_t)n * 64;
    float* o_lv    = out + (size_t)n * 80;
    float* o_gat   = out + (size_t)n * 96;

    const int bpc = (n + 255) / 256;     // node blocks
    const int ebl = (E + 255) / 256;     // edge blocks
    const int nbS = (n + 255) / 256;     // scan blocks (<=512 for n<=131072)
    const int abl = (n * 64 + 255) / 256;// agg blocks (wave per dst)

    // --- CSR build (shared by both layers) ---
    hipMemsetAsync(deg, 0, (size_t)n * 4, stream);
    count_k<<<ebl, 256, 0, stream>>>(ei, deg, E);
    scanA_k<<<nbS, 256, 0, stream>>>(deg, incl, bsum, n);
    scanB_k<<<1, 512, 0, stream>>>(bsum, nbS);
    scanC_k<<<nbS, 256, 0, stream>>>(deg, incl, bsum, off, cursor, n, E);
    scatter_k<<<ebl, 256, 0, stream>>>(ei, cursor, csr, E);

    // --- GAT layer 1 ---
    gemm_k<128, 128, 32, 0><<<bpc * 4, 256, 0, stream>>>(x, W1, nullptr, h1, n, bpc);
    attn_dots_k<2, 64><<<(n * 2 + 255) / 256, 256, 0, stream>>>(h1, as1w, ad1w, as1, ad1, n);
    gat_agg_k<128, 2, 1><<<abl, 256, 0, stream>>>(csr, off, as1, ad1, h1, b1, hl2, n);

    // --- GAT layer 2 ---
    gemm_k<128, 64, 32, 0><<<bpc * 2, 256, 0, stream>>>(hl2, W2, nullptr, h2, n, bpc);
    attn_dots_k<1, 64><<<(n + 255) / 256, 256, 0, stream>>>(h2, as2w, ad2w, as2, ad2, n);
    gat_agg_k<64, 1, 0><<<abl, 256, 0, stream>>>(csr, off, as2, ad2, h2, b2, o_gat, n);

    // --- VAE ---
    gemm_k<64, 128, 32, 1><<<bpc * 4, 256, 0, stream>>>(o_gat, fc1w, fc1b, h1v, n, bpc);
    gemm_k<128, 16, 16, 0><<<bpc, 256, 0, stream>>>(h1v, muw, mub, o_mu, n, bpc);
    gemm_k<128, 16, 16, 0><<<bpc, 256, 0, stream>>>(h1v, lvw, lvb, o_lv, n, bpc);
    z_k<<<(n * 16 + 255) / 256, 256, 0, stream>>>(o_mu, o_lv, eps, zb, n * 16);
    gemm_k<16, 128, 32, 1><<<bpc * 4, 256, 0, stream>>>(zb, fc3w, fc3b, h3, n, bpc);
    gemm_k<128, 64, 32, 0><<<bpc * 2, 256, 0, stream>>>(h3, fc4w, fc4b, o_recon, n, bpc);
}

// Round 4
// 743.625 us; speedup vs baseline: 4.0426x; 1.4772x over previous
//
#include <hip/hip_runtime.h>
#include <hip/hip_bf16.h>

__device__ __forceinline__ float4 fma4(float s, float4 b, float4 c) {
    c.x = fmaf(s, b.x, c.x); c.y = fmaf(s, b.y, c.y);
    c.z = fmaf(s, b.z, c.z); c.w = fmaf(s, b.w, c.w);
    return c;
}

// ---------------- LDS-tiled node GEMM: out = act(A @ W + bias) ----------------
// A: f32 [n, FIN]; W: f32 [FIN, FOUT]; out: f32 [n, FOUT]. BM=128 rows/block.
template<int FIN, int FOUT, int BK, int ACT>
__global__ __launch_bounds__(256) void tgemm_k(const float* __restrict__ A,
                                               const float* __restrict__ W,
                                               const float* __restrict__ bias,
                                               float* __restrict__ out, int n)
{
    constexpr int BM  = 128;
    constexpr int BMp = BM + 4;
    constexpr int NT_N = FOUT / 4;        // threads across columns (one float4 each)
    constexpr int NT_M = 256 / NT_N;      // threads across rows
    constexpr int RG   = (BM / NT_M) / 4; // 4-row groups per thread
    __shared__ __align__(16) float As[BK * BMp];   // transposed: As[k][m]
    __shared__ __align__(16) float Bs[BK * FOUT];  // Bs[k][nn]

    const int t  = threadIdx.x;
    const int m0 = blockIdx.x * BM;
    const int tn = t % NT_N, tm = t / NT_N;

    float4 acc[RG][4];
    #pragma unroll
    for (int g = 0; g < RG; ++g)
        #pragma unroll
        for (int i = 0; i < 4; ++i) acc[g][i] = make_float4(0.f, 0.f, 0.f, 0.f);

    for (int kt = 0; kt < FIN; kt += BK) {
        __syncthreads();
        // stage A-tile transposed (each x element fetched exactly once per block)
        #pragma unroll
        for (int idx = t; idx < BM * BK / 4; idx += 256) {
            int r  = idx / (BK / 4);
            int c4 = (idx % (BK / 4)) * 4;
            int row = m0 + r;
            float4 v = make_float4(0.f, 0.f, 0.f, 0.f);
            if (row < n) v = *(const float4*)(A + (size_t)row * FIN + kt + c4);
            As[(c4 + 0) * BMp + r] = v.x;
            As[(c4 + 1) * BMp + r] = v.y;
            As[(c4 + 2) * BMp + r] = v.z;
            As[(c4 + 3) * BMp + r] = v.w;
        }
        // stage B-tile
        #pragma unroll
        for (int idx = t; idx < BK * FOUT / 4; idx += 256) {
            int kr = idx / (FOUT / 4);
            int c4 = (idx % (FOUT / 4)) * 4;
            *(float4*)(Bs + kr * FOUT + c4) =
                *(const float4*)(W + (size_t)(kt + kr) * FOUT + c4);
        }
        __syncthreads();
        #pragma unroll 8
        for (int k = 0; k < BK; ++k) {
            float4 b = *(const float4*)(Bs + k * FOUT + 4 * tn);
            #pragma unroll
            for (int g = 0; g < RG; ++g) {
                float4 a = *(const float4*)(As + k * BMp + 4 * (tm + NT_M * g));
                acc[g][0] = fma4(a.x, b, acc[g][0]);
                acc[g][1] = fma4(a.y, b, acc[g][1]);
                acc[g][2] = fma4(a.z, b, acc[g][2]);
                acc[g][3] = fma4(a.w, b, acc[g][3]);
            }
        }
    }

    float4 bb = make_float4(0.f, 0.f, 0.f, 0.f);
    if (bias) bb = *(const float4*)(bias + 4 * tn);
    #pragma unroll
    for (int g = 0; g < RG; ++g)
        #pragma unroll
        for (int i = 0; i < 4; ++i) {
            int row = m0 + 4 * (tm + NT_M * g) + i;
            if (row < n) {
                float4 o = acc[g][i];
                o.x += bb.x; o.y += bb.y; o.z += bb.z; o.w += bb.w;
                if (ACT == 1) {
                    o.x = fmaxf(o.x, 0.f); o.y = fmaxf(o.y, 0.f);
                    o.z = fmaxf(o.z, 0.f); o.w = fmaxf(o.w, 0.f);
                }
                *(float4*)(out + (size_t)row * FOUT + 4 * tn) = o;
            }
        }
}

// ---------------- fused mu/logvar GEMM + reparameterize ----------------
// h: f32 [n,128]; muw/lvw: [128,16]; writes o_mu, o_lv, z (= mu + eps*exp(0.5*clip(lv)))
__global__ __launch_bounds__(256) void mulv_k(const float* __restrict__ A,
                                              const float* __restrict__ muw,
                                              const float* __restrict__ lvw,
                                              const float* __restrict__ mub,
                                              const float* __restrict__ lvb,
                                              const float* __restrict__ eps,
                                              float* __restrict__ o_mu,
                                              float* __restrict__ o_lv,
                                              float* __restrict__ zb, int n)
{
    constexpr int FIN = 128, BK = 32, BN = 32;
    constexpr int BM = 128, BMp = BM + 4;
    constexpr int NT_N = BN / 4;      // 8
    constexpr int NT_M = 256 / NT_N;  // 32
    __shared__ __align__(16) float As[BK * BMp];
    __shared__ __align__(16) float Bs[BK * BN];

    const int t  = threadIdx.x;
    const int m0 = blockIdx.x * BM;
    const int tn = t % NT_N, tm = t / NT_N;

    float4 acc[4];
    #pragma unroll
    for (int i = 0; i < 4; ++i) acc[i] = make_float4(0.f, 0.f, 0.f, 0.f);

    for (int kt = 0; kt < FIN; kt += BK) {
        __syncthreads();
        #pragma unroll
        for (int idx = t; idx < BM * BK / 4; idx += 256) {
            int r  = idx / (BK / 4);
            int c4 = (idx % (BK / 4)) * 4;
            int row = m0 + r;
            float4 v = make_float4(0.f, 0.f, 0.f, 0.f);
            if (row < n) v = *(const float4*)(A + (size_t)row * FIN + kt + c4);
            As[(c4 + 0) * BMp + r] = v.x;
            As[(c4 + 1) * BMp + r] = v.y;
            As[(c4 + 2) * BMp + r] = v.z;
            As[(c4 + 3) * BMp + r] = v.w;
        }
        {   // B: cols 0..15 = muw, 16..31 = lvw   (BK*BN/4 = 256 = one per thread)
            int kr = t / 8, c4 = (t % 8) * 4;
            const float* src = (c4 < 16) ? (muw + (size_t)(kt + kr) * 16 + c4)
                                         : (lvw + (size_t)(kt + kr) * 16 + (c4 - 16));
            *(float4*)(Bs + kr * BN + c4) = *(const float4*)src;
        }
        __syncthreads();
        #pragma unroll 8
        for (int k = 0; k < BK; ++k) {
            float4 b = *(const float4*)(Bs + k * BN + 4 * tn);
            float4 a = *(const float4*)(As + k * BMp + 4 * tm);
            acc[0] = fma4(a.x, b, acc[0]);
            acc[1] = fma4(a.y, b, acc[1]);
            acc[2] = fma4(a.z, b, acc[2]);
            acc[3] = fma4(a.w, b, acc[3]);
        }
    }

    const bool is_mu = (tn < 4);
    const int  c16   = is_mu ? 4 * tn : 4 * tn - 16;
    float4 bb = is_mu ? *(const float4*)(mub + c16) : *(const float4*)(lvb + c16);

    #pragma unroll
    for (int i = 0; i < 4; ++i) {
        int row = m0 + 4 * tm + i;
        float4 v = acc[i];
        v.x += bb.x; v.y += bb.y; v.z += bb.z; v.w += bb.w;
        // exchange: mu-lanes receive raw logvar from lane+4 (same tm, tn^4)
        float4 lvx;
        lvx.x = __shfl_xor(v.x, 4, 64);
        lvx.y = __shfl_xor(v.y, 4, 64);
        lvx.z = __shfl_xor(v.z, 4, 64);
        lvx.w = __shfl_xor(v.w, 4, 64);
        if (row < n) {
            if (is_mu) {
                *(float4*)(o_mu + (size_t)row * 16 + c16) = v;
                float4 ep = *(const float4*)(eps + (size_t)row * 16 + c16);
                float4 z;
                z.x = fmaf(ep.x, __expf(0.5f * fminf(fmaxf(lvx.x, -10.f), 10.f)), v.x);
                z.y = fmaf(ep.y, __expf(0.5f * fminf(fmaxf(lvx.y, -10.f), 10.f)), v.y);
                z.z = fmaf(ep.z, __expf(0.5f * fminf(fmaxf(lvx.z, -10.f), 10.f)), v.z);
                z.w = fmaf(ep.w, __expf(0.5f * fminf(fmaxf(lvx.w, -10.f), 10.f)), v.w);
                *(float4*)(zb + (size_t)row * 16 + c16) = z;
            } else {
                *(float4*)(o_lv + (size_t)row * 16 + c16) = v;   // unclipped, per reference
            }
        }
    }
}

// ---------------- per-node attention dot products ----------------
template<int H, int D>
__global__ __launch_bounds__(256) void attn_dots_k(const float* __restrict__ h,
                                                   const float* __restrict__ asr,
                                                   const float* __restrict__ adr,
                                                   float* __restrict__ as_o,
                                                   float* __restrict__ ad_o, int n)
{
    int t = blockIdx.x * 256 + threadIdx.x;
    if (t >= n * H) return;
    int node = t / H, hd = t - node * H;
    const float* row = h + (size_t)node * (H * D) + hd * D;
    const float* av = asr + hd * D;
    const float* bv = adr + hd * D;
    float ds = 0.f, dd = 0.f;
    #pragma unroll 1
    for (int k4 = 0; k4 < D; k4 += 4) {
        float4 v = *(const float4*)(row + k4);
        ds = fmaf(v.x, av[k4], fmaf(v.y, av[k4 + 1], fmaf(v.z, av[k4 + 2], fmaf(v.w, av[k4 + 3], ds))));
        dd = fmaf(v.x, bv[k4], fmaf(v.y, bv[k4 + 1], fmaf(v.z, bv[k4 + 2], fmaf(v.w, bv[k4 + 3], dd))));
    }
    as_o[t] = ds;
    ad_o[t] = dd;
}

// ---------------- CSR build ----------------
__global__ __launch_bounds__(256) void count_k(const int* __restrict__ ei, int* __restrict__ deg, int E)
{
    int e = blockIdx.x * 256 + threadIdx.x;
    if (e >= E) return;
    atomicAdd(&deg[ei[E + e]], 1);
}

__global__ __launch_bounds__(256) void scanA_k(const int* __restrict__ deg, int* __restrict__ incl,
                                               int* __restrict__ bsum, int n)
{
    __shared__ int sh[256];
    int i = blockIdx.x * 256 + threadIdx.x;
    int v = (i < n) ? deg[i] : 0;
    sh[threadIdx.x] = v;
    __syncthreads();
    #pragma unroll
    for (int o = 1; o < 256; o <<= 1) {
        int t = (threadIdx.x >= o) ? sh[threadIdx.x - o] : 0;
        __syncthreads();
        sh[threadIdx.x] += t;
        __syncthreads();
    }
    if (i < n) incl[i] = sh[threadIdx.x];
    if (threadIdx.x == 255) bsum[blockIdx.x] = sh[255];
}

__global__ __launch_bounds__(512) void scanB_k(int* __restrict__ bsum, int nb)
{
    __shared__ int sh[512];
    int v = (threadIdx.x < nb) ? bsum[threadIdx.x] : 0;
    sh[threadIdx.x] = v;
    __syncthreads();
    #pragma unroll
    for (int o = 1; o < 512; o <<= 1) {
        int t = (threadIdx.x >= o) ? sh[threadIdx.x - o] : 0;
        __syncthreads();
        sh[threadIdx.x] += t;
        __syncthreads();
    }
    if (threadIdx.x < nb) bsum[threadIdx.x] = sh[threadIdx.x] - v;   // exclusive
}

__global__ __launch_bounds__(256) void scanC_k(const int* __restrict__ deg, const int* __restrict__ incl,
                                               const int* __restrict__ bsum, int* __restrict__ off,
                                               int* __restrict__ cursor, int n, int E)
{
    int i = blockIdx.x * 256 + threadIdx.x;
    if (i >= n) return;
    int v = incl[i] - deg[i] + bsum[i >> 8];
    off[i] = v;
    cursor[i] = v;
    if (i == 0) off[n] = E;
}

__global__ __launch_bounds__(256) void scatter_k(const int* __restrict__ ei, int* __restrict__ cursor,
                                                 int* __restrict__ csr_src, int E)
{
    int e = blockIdx.x * 256 + threadIdx.x;
    if (e >= E) return;
    int s = ei[e], d = ei[E + e];
    int pos = atomicAdd(&cursor[d], 1);
    csr_src[pos] = s;
}

// ---------------- fused per-dst softmax + aggregate (wave-per-dst) ----------------
template<int FEAT, int H, int ACT>
__global__ __launch_bounds__(256) void gat_agg_k(const int* __restrict__ csr_src,
                                                 const int* __restrict__ off,
                                                 const float* __restrict__ as_,
                                                 const float* __restrict__ ad_,
                                                 const float* __restrict__ h,
                                                 const float* __restrict__ bias,
                                                 float* __restrict__ out, int n)
{
    constexpr int FPL = FEAT / 64;
    constexpr int D = FEAT / H;
    int wid = (blockIdx.x * 256 + threadIdx.x) >> 6;
    if (wid >= n) return;
    const int lane = threadIdx.x & 63;
    const int d = wid;
    const int start = off[d], end = off[d + 1];

    float adv[H];
    #pragma unroll
    for (int hh = 0; hh < H; ++hh) adv[hh] = ad_[d * H + hh];

    float m[H];
    #pragma unroll
    for (int hh = 0; hh < H; ++hh) m[hh] = -3.4e38f;
    for (int j = start + lane; j < end; j += 64) {
        int s = csr_src[j];
        #pragma unroll
        for (int hh = 0; hh < H; ++hh) {
            float v = as_[s * H + hh] + adv[hh];
            v = v > 0.f ? v : 0.2f * v;
            m[hh] = fmaxf(m[hh], v);
        }
    }
    #pragma unroll
    for (int hh = 0; hh < H; ++hh)
        for (int o = 32; o > 0; o >>= 1)
            m[hh] = fmaxf(m[hh], __shfl_xor(m[hh], o, 64));

    float den[H];
    #pragma unroll
    for (int hh = 0; hh < H; ++hh) den[hh] = 0.f;
    for (int j = start + lane; j < end; j += 64) {
        int s = csr_src[j];
        #pragma unroll
        for (int hh = 0; hh < H; ++hh) {
            float v = as_[s * H + hh] + adv[hh];
            v = v > 0.f ? v : 0.2f * v;
            den[hh] += __expf(v - m[hh]);
        }
    }
    #pragma unroll
    for (int hh = 0; hh < H; ++hh)
        for (int o = 32; o > 0; o >>= 1)
            den[hh] += __shfl_xor(den[hh], o, 64);

    const int myhead = (lane * FPL) / D;
    const float mh = m[myhead];
    const float inv = 1.f / (den[myhead] + 1e-16f);
    const float adm = adv[myhead];
    float acc[FPL];
    #pragma unroll
    for (int k = 0; k < FPL; ++k) acc[k] = 0.f;

    int j = start;
    for (; j + 1 < end; j += 2) {
        int s0 = csr_src[j], s1 = csr_src[j + 1];
        float v0 = as_[s0 * H + myhead] + adm; v0 = v0 > 0.f ? v0 : 0.2f * v0;
        float v1 = as_[s1 * H + myhead] + adm; v1 = v1 > 0.f ? v1 : 0.2f * v1;
        float a0 = __expf(v0 - mh) * inv;
        float a1 = __expf(v1 - mh) * inv;
        const float* r0 = h + (size_t)s0 * FEAT + lane * FPL;
        const float* r1 = h + (size_t)s1 * FEAT + lane * FPL;
        if constexpr (FPL == 2) {
            float2 x0 = *(const float2*)r0;
            float2 x1 = *(const float2*)r1;
            acc[0] = fmaf(x0.x, a0, fmaf(x1.x, a1, acc[0]));
            acc[1] = fmaf(x0.y, a0, fmaf(x1.y, a1, acc[1]));
        } else {
            acc[0] = fmaf(r0[0], a0, fmaf(r1[0], a1, acc[0]));
        }
    }
    for (; j < end; ++j) {
        int s0 = csr_src[j];
        float v0 = as_[s0 * H + myhead] + adm; v0 = v0 > 0.f ? v0 : 0.2f * v0;
        float a0 = __expf(v0 - mh) * inv;
        const float* r0 = h + (size_t)s0 * FEAT + lane * FPL;
        if constexpr (FPL == 2) {
            float2 x0 = *(const float2*)r0;
            acc[0] = fmaf(x0.x, a0, acc[0]);
            acc[1] = fmaf(x0.y, a0, acc[1]);
        } else {
            acc[0] = fmaf(r0[0], a0, acc[0]);
        }
    }

    #pragma unroll
    for (int k = 0; k < FPL; ++k) {
        float o = acc[k] + bias[lane * FPL + k];
        if (ACT == 1) o = fmaxf(o, 0.f);
        out[(size_t)d * FEAT + lane * FPL + k] = o;
    }
}

// ---------------- launch ----------------
extern "C" void kernel_launch(void* const* d_in, const int* in_sizes, int n_in,
                              void* d_out, int out_size, void* d_ws, size_t ws_size,
                              hipStream_t stream)
{
    const int n = in_sizes[0] / 128;     // N nodes
    const int E = in_sizes[1] / 2;       // edges

    const float* x   = (const float*)d_in[0];
    const int*   ei  = (const int*)d_in[1];
    const float* eps = (const float*)d_in[3];
    const float* W1  = (const float*)d_in[4];
    const float* as1w= (const float*)d_in[5];
    const float* ad1w= (const float*)d_in[6];
    const float* b1  = (const float*)d_in[7];
    const float* W2  = (const float*)d_in[8];
    const float* as2w= (const float*)d_in[9];
    const float* ad2w= (const float*)d_in[10];
    const float* b2  = (const float*)d_in[11];
    const float* fc1w= (const float*)d_in[12];
    const float* fc1b= (const float*)d_in[13];
    const float* muw = (const float*)d_in[14];
    const float* mub = (const float*)d_in[15];
    const float* lvw = (const float*)d_in[16];
    const float* lvb = (const float*)d_in[17];
    const float* fc3w= (const float*)d_in[18];
    const float* fc3b= (const float*)d_in[19];
    const float* fc4w= (const float*)d_in[20];
    const float* fc4b= (const float*)d_in[21];

    char* ws = (char*)d_ws;

    size_t oDeg   = 0;
    size_t oOff   = oDeg  + (size_t)n * 4;
    size_t oIncl  = oOff  + (size_t)(n + 1) * 4;
    size_t oCur   = oIncl + (size_t)n * 4;
    size_t oBsum  = oCur  + (size_t)n * 4;
    size_t oCsr   = oBsum + 512 * 4;
    size_t oH1    = oCsr  + (size_t)E * 4;
    size_t oHl2   = oH1   + (size_t)n * 128 * 4;
    size_t oH2    = oHl2  + (size_t)n * 128 * 4;
    size_t oAS1   = oH2   + (size_t)n * 64 * 4;
    size_t oAD1   = oAS1  + (size_t)n * 2 * 4;
    size_t oAS2   = oAD1  + (size_t)n * 2 * 4;
    size_t oAD2   = oAS2  + (size_t)n * 4;

    int* deg    = (int*)(ws + oDeg);
    int* off    = (int*)(ws + oOff);
    int* incl   = (int*)(ws + oIncl);
    int* cursor = (int*)(ws + oCur);
    int* bsum   = (int*)(ws + oBsum);
    int* csr    = (int*)(ws + oCsr);
    float* h1   = (float*)(ws + oH1);
    float* hl2  = (float*)(ws + oHl2);
    float* h2   = (float*)(ws + oH2);
    float* as1  = (float*)(ws + oAS1);
    float* ad1  = (float*)(ws + oAD1);
    float* as2  = (float*)(ws + oAS2);
    float* ad2  = (float*)(ws + oAD2);
    float* h1v  = h1;     // reuse
    float* h3   = h1;     // reuse
    float* zb   = h2;     // reuse

    float* out     = (float*)d_out;
    float* o_recon = out;
    float* o_mu    = out + (size_t)n * 64;
    float* o_lv    = out + (size_t)n * 80;
    float* o_gat   = out + (size_t)n * 96;

    const int ebl  = (E + 255) / 256;
    const int nbS  = (n + 255) / 256;
    const int abl  = (n * 64 + 255) / 256;
    const int gblk = (n + 127) / 128;

    // --- CSR build ---
    hipMemsetAsync(deg, 0, (size_t)n * 4, stream);
    count_k<<<ebl, 256, 0, stream>>>(ei, deg, E);
    scanA_k<<<nbS, 256, 0, stream>>>(deg, incl, bsum, n);
    scanB_k<<<1, 512, 0, stream>>>(bsum, nbS);
    scanC_k<<<nbS, 256, 0, stream>>>(deg, incl, bsum, off, cursor, n, E);
    scatter_k<<<ebl, 256, 0, stream>>>(ei, cursor, csr, E);

    // --- GAT layer 1 ---
    tgemm_k<128, 128, 32, 0><<<gblk, 256, 0, stream>>>(x, W1, nullptr, h1, n);
    attn_dots_k<2, 64><<<(n * 2 + 255) / 256, 256, 0, stream>>>(h1, as1w, ad1w, as1, ad1, n);
    gat_agg_k<128, 2, 1><<<abl, 256, 0, stream>>>(csr, off, as1, ad1, h1, b1, hl2, n);

    // --- GAT layer 2 ---
    tgemm_k<128, 64, 32, 0><<<gblk, 256, 0, stream>>>(hl2, W2, nullptr, h2, n);
    attn_dots_k<1, 64><<<(n + 255) / 256, 256, 0, stream>>>(h2, as2w, ad2w, as2, ad2, n);
    gat_agg_k<64, 1, 0><<<abl, 256, 0, stream>>>(csr, off, as2, ad2, h2, b2, o_gat, n);

    // --- VAE ---
    tgemm_k<64, 128, 32, 1><<<gblk, 256, 0, stream>>>(o_gat, fc1w, fc1b, h1v, n);
    mulv_k<<<gblk, 256, 0, stream>>>(h1v, muw, lvw, mub, lvb, eps, o_mu, o_lv, zb, n);
    tgemm_k<16, 128, 16, 1><<<gblk, 256, 0, stream>>>(zb, fc3w, fc3b, h3, n);
    tgemm_k<128, 64, 32, 0><<<gblk, 256, 0, stream>>>(h3, fc4w, fc4b, o_recon, n);
}

// Round 5
// 602.479 us; speedup vs baseline: 4.9897x; 1.2343x over previous
//
#include <hip/hip_runtime.h>
#include <hip/hip_bf16.h>

__device__ __forceinline__ float4 fma4(float s, float4 b, float4 c) {
    c.x = fmaf(s, b.x, c.x); c.y = fmaf(s, b.y, c.y);
    c.z = fmaf(s, b.z, c.z); c.w = fmaf(s, b.w, c.w);
    return c;
}

__device__ __forceinline__ unsigned short f2b_bits(float x) {
    __hip_bfloat16 h = __float2bfloat16(x);
    unsigned short u;
    __builtin_memcpy(&u, &h, 2);
    return u;
}
__device__ __forceinline__ unsigned int pack2(float a, float b) {
    return (unsigned int)f2b_bits(a) | ((unsigned int)f2b_bits(b) << 16);
}
__device__ __forceinline__ float blo(unsigned int u) { return __uint_as_float(u << 16); }
__device__ __forceinline__ float bhi(unsigned int u) { return __uint_as_float(u & 0xffff0000u); }

// ---------------- LDS-tiled node GEMM: out = act(A @ W + bias) ----------------
// A: f32 [n, FIN]; W: f32 [FIN, FOUT]; out: f32 or bf16 [n, FOUT]. BM=128 rows/block.
template<int FIN, int FOUT, int BK, int ACT, bool OBF>
__global__ __launch_bounds__(256) void tgemm_k(const float* __restrict__ A,
                                               const float* __restrict__ W,
                                               const float* __restrict__ bias,
                                               void* __restrict__ outv, int n)
{
    constexpr int BM  = 128;
    constexpr int BMp = BM + 4;
    constexpr int NT_N = FOUT / 4;
    constexpr int NT_M = 256 / NT_N;
    constexpr int RG   = (BM / NT_M) / 4;
    __shared__ __align__(16) float As[BK * BMp];
    __shared__ __align__(16) float Bs[BK * FOUT];

    const int t  = threadIdx.x;
    const int m0 = blockIdx.x * BM;
    const int tn = t % NT_N, tm = t / NT_N;

    float4 acc[RG][4];
    #pragma unroll
    for (int g = 0; g < RG; ++g)
        #pragma unroll
        for (int i = 0; i < 4; ++i) acc[g][i] = make_float4(0.f, 0.f, 0.f, 0.f);

    for (int kt = 0; kt < FIN; kt += BK) {
        __syncthreads();
        #pragma unroll
        for (int idx = t; idx < BM * BK / 4; idx += 256) {
            int r  = idx / (BK / 4);
            int c4 = (idx % (BK / 4)) * 4;
            int row = m0 + r;
            float4 v = make_float4(0.f, 0.f, 0.f, 0.f);
            if (row < n) v = *(const float4*)(A + (size_t)row * FIN + kt + c4);
            As[(c4 + 0) * BMp + r] = v.x;
            As[(c4 + 1) * BMp + r] = v.y;
            As[(c4 + 2) * BMp + r] = v.z;
            As[(c4 + 3) * BMp + r] = v.w;
        }
        #pragma unroll
        for (int idx = t; idx < BK * FOUT / 4; idx += 256) {
            int kr = idx / (FOUT / 4);
            int c4 = (idx % (FOUT / 4)) * 4;
            *(float4*)(Bs + kr * FOUT + c4) =
                *(const float4*)(W + (size_t)(kt + kr) * FOUT + c4);
        }
        __syncthreads();
        #pragma unroll 8
        for (int k = 0; k < BK; ++k) {
            float4 b = *(const float4*)(Bs + k * FOUT + 4 * tn);
            #pragma unroll
            for (int g = 0; g < RG; ++g) {
                float4 a = *(const float4*)(As + k * BMp + 4 * (tm + NT_M * g));
                acc[g][0] = fma4(a.x, b, acc[g][0]);
                acc[g][1] = fma4(a.y, b, acc[g][1]);
                acc[g][2] = fma4(a.z, b, acc[g][2]);
                acc[g][3] = fma4(a.w, b, acc[g][3]);
            }
        }
    }

    float4 bb = make_float4(0.f, 0.f, 0.f, 0.f);
    if (bias) bb = *(const float4*)(bias + 4 * tn);
    #pragma unroll
    for (int g = 0; g < RG; ++g)
        #pragma unroll
        for (int i = 0; i < 4; ++i) {
            int row = m0 + 4 * (tm + NT_M * g) + i;
            if (row < n) {
                float4 o = acc[g][i];
                o.x += bb.x; o.y += bb.y; o.z += bb.z; o.w += bb.w;
                if (ACT == 1) {
                    o.x = fmaxf(o.x, 0.f); o.y = fmaxf(o.y, 0.f);
                    o.z = fmaxf(o.z, 0.f); o.w = fmaxf(o.w, 0.f);
                }
                if constexpr (OBF) {
                    unsigned short* outb = (unsigned short*)outv;
                    uint2 pv = make_uint2(pack2(o.x, o.y), pack2(o.z, o.w));
                    *(uint2*)(outb + (size_t)row * FOUT + 4 * tn) = pv;
                } else {
                    float* outf = (float*)outv;
                    *(float4*)(outf + (size_t)row * FOUT + 4 * tn) = o;
                }
            }
        }
}

// ---------------- fused mu/logvar GEMM + reparameterize ----------------
__global__ __launch_bounds__(256) void mulv_k(const float* __restrict__ A,
                                              const float* __restrict__ muw,
                                              const float* __restrict__ lvw,
                                              const float* __restrict__ mub,
                                              const float* __restrict__ lvb,
                                              const float* __restrict__ eps,
                                              float* __restrict__ o_mu,
                                              float* __restrict__ o_lv,
                                              float* __restrict__ zb, int n)
{
    constexpr int FIN = 128, BK = 32, BN = 32;
    constexpr int BM = 128, BMp = BM + 4;
    constexpr int NT_N = BN / 4;      // 8
    __shared__ __align__(16) float As[BK * BMp];
    __shared__ __align__(16) float Bs[BK * BN];

    const int t  = threadIdx.x;
    const int m0 = blockIdx.x * BM;
    const int tn = t % NT_N, tm = t / NT_N;

    float4 acc[4];
    #pragma unroll
    for (int i = 0; i < 4; ++i) acc[i] = make_float4(0.f, 0.f, 0.f, 0.f);

    for (int kt = 0; kt < FIN; kt += BK) {
        __syncthreads();
        #pragma unroll
        for (int idx = t; idx < BM * BK / 4; idx += 256) {
            int r  = idx / (BK / 4);
            int c4 = (idx % (BK / 4)) * 4;
            int row = m0 + r;
            float4 v = make_float4(0.f, 0.f, 0.f, 0.f);
            if (row < n) v = *(const float4*)(A + (size_t)row * FIN + kt + c4);
            As[(c4 + 0) * BMp + r] = v.x;
            As[(c4 + 1) * BMp + r] = v.y;
            As[(c4 + 2) * BMp + r] = v.z;
            As[(c4 + 3) * BMp + r] = v.w;
        }
        {
            int kr = t / 8, c4 = (t % 8) * 4;
            const float* src = (c4 < 16) ? (muw + (size_t)(kt + kr) * 16 + c4)
                                         : (lvw + (size_t)(kt + kr) * 16 + (c4 - 16));
            *(float4*)(Bs + kr * BN + c4) = *(const float4*)src;
        }
        __syncthreads();
        #pragma unroll 8
        for (int k = 0; k < BK; ++k) {
            float4 b = *(const float4*)(Bs + k * BN + 4 * tn);
            float4 a = *(const float4*)(As + k * BMp + 4 * tm);
            acc[0] = fma4(a.x, b, acc[0]);
            acc[1] = fma4(a.y, b, acc[1]);
            acc[2] = fma4(a.z, b, acc[2]);
            acc[3] = fma4(a.w, b, acc[3]);
        }
    }

    const bool is_mu = (tn < 4);
    const int  c16   = is_mu ? 4 * tn : 4 * tn - 16;
    float4 bb = is_mu ? *(const float4*)(mub + c16) : *(const float4*)(lvb + c16);

    #pragma unroll
    for (int i = 0; i < 4; ++i) {
        int row = m0 + 4 * tm + i;
        float4 v = acc[i];
        v.x += bb.x; v.y += bb.y; v.z += bb.z; v.w += bb.w;
        float4 lvx;
        lvx.x = __shfl_xor(v.x, 4, 64);
        lvx.y = __shfl_xor(v.y, 4, 64);
        lvx.z = __shfl_xor(v.z, 4, 64);
        lvx.w = __shfl_xor(v.w, 4, 64);
        if (row < n) {
            if (is_mu) {
                *(float4*)(o_mu + (size_t)row * 16 + c16) = v;
                float4 ep = *(const float4*)(eps + (size_t)row * 16 + c16);
                float4 z;
                z.x = fmaf(ep.x, __expf(0.5f * fminf(fmaxf(lvx.x, -10.f), 10.f)), v.x);
                z.y = fmaf(ep.y, __expf(0.5f * fminf(fmaxf(lvx.y, -10.f), 10.f)), v.y);
                z.z = fmaf(ep.z, __expf(0.5f * fminf(fmaxf(lvx.z, -10.f), 10.f)), v.z);
                z.w = fmaf(ep.w, __expf(0.5f * fminf(fmaxf(lvx.w, -10.f), 10.f)), v.w);
                *(float4*)(zb + (size_t)row * 16 + c16) = z;
            } else {
                *(float4*)(o_lv + (size_t)row * 16 + c16) = v;
            }
        }
    }
}

// ---------------- per-node attention dot products (bf16 h) ----------------
template<int H, int D>
__global__ __launch_bounds__(256) void attn_dots_k(const unsigned short* __restrict__ h,
                                                   const float* __restrict__ asr,
                                                   const float* __restrict__ adr,
                                                   float* __restrict__ as_o,
                                                   float* __restrict__ ad_o, int n)
{
    int t = blockIdx.x * 256 + threadIdx.x;
    if (t >= n * H) return;
    int node = t / H, hd = t - node * H;
    const uint4* row = (const uint4*)(h + (size_t)node * (H * D) + hd * D);
    const float* av = asr + hd * D;
    const float* bv = adr + hd * D;
    float ds = 0.f, dd = 0.f;
    #pragma unroll 1
    for (int k8 = 0; k8 < D; k8 += 8) {
        uint4 r = row[k8 >> 3];
        float v[8] = { blo(r.x), bhi(r.x), blo(r.y), bhi(r.y),
                       blo(r.z), bhi(r.z), blo(r.w), bhi(r.w) };
        #pragma unroll
        for (int u = 0; u < 8; ++u) {
            ds = fmaf(v[u], av[k8 + u], ds);
            dd = fmaf(v[u], bv[k8 + u], dd);
        }
    }
    as_o[t] = ds;
    ad_o[t] = dd;
}

// ---------------- CSR build ----------------
__global__ __launch_bounds__(256) void count_k(const int* __restrict__ ei, int* __restrict__ deg, int E)
{
    int e = blockIdx.x * 256 + threadIdx.x;
    if (e >= E) return;
    atomicAdd(&deg[ei[E + e]], 1);
}

__global__ __launch_bounds__(256) void scanA_k(const int* __restrict__ deg, int* __restrict__ incl,
                                               int* __restrict__ bsum, int n)
{
    __shared__ int sh[256];
    int i = blockIdx.x * 256 + threadIdx.x;
    int v = (i < n) ? deg[i] : 0;
    sh[threadIdx.x] = v;
    __syncthreads();
    #pragma unroll
    for (int o = 1; o < 256; o <<= 1) {
        int t = (threadIdx.x >= o) ? sh[threadIdx.x - o] : 0;
        __syncthreads();
        sh[threadIdx.x] += t;
        __syncthreads();
    }
    if (i < n) incl[i] = sh[threadIdx.x];
    if (threadIdx.x == 255) bsum[blockIdx.x] = sh[255];
}

__global__ __launch_bounds__(512) void scanB_k(int* __restrict__ bsum, int nb)
{
    __shared__ int sh[512];
    int v = (threadIdx.x < nb) ? bsum[threadIdx.x] : 0;
    sh[threadIdx.x] = v;
    __syncthreads();
    #pragma unroll
    for (int o = 1; o < 512; o <<= 1) {
        int t = (threadIdx.x >= o) ? sh[threadIdx.x - o] : 0;
        __syncthreads();
        sh[threadIdx.x] += t;
        __syncthreads();
    }
    if (threadIdx.x < nb) bsum[threadIdx.x] = sh[threadIdx.x] - v;
}

__global__ __launch_bounds__(256) void scanC_k(const int* __restrict__ deg, const int* __restrict__ incl,
                                               const int* __restrict__ bsum, int* __restrict__ off,
                                               int* __restrict__ cursor, int n, int E)
{
    int i = blockIdx.x * 256 + threadIdx.x;
    if (i >= n) return;
    int v = incl[i] - deg[i] + bsum[i >> 8];
    off[i] = v;
    cursor[i] = v;
    if (i == 0) off[n] = E;
}

__global__ __launch_bounds__(256) void scatter_k(const int* __restrict__ ei, int* __restrict__ cursor,
                                                 int* __restrict__ csr_src, int E)
{
    int e = blockIdx.x * 256 + threadIdx.x;
    if (e >= E) return;
    int s = ei[e], d = ei[E + e];
    int pos = atomicAdd(&cursor[d], 1);
    csr_src[pos] = s;
}

// ---------------- fused per-dst softmax + aggregate ----------------
// 16 lanes per dst (4 dsts/wave); h gathered as bf16; online softmax (single pass).
template<int FEAT, int H, int ACT>
__global__ __launch_bounds__(256) void gat_agg_k(const int* __restrict__ csr_src,
                                                 const int* __restrict__ off,
                                                 const float* __restrict__ as_,
                                                 const float* __restrict__ ad_,
                                                 const unsigned short* __restrict__ hb,
                                                 const float* __restrict__ bias,
                                                 float* __restrict__ out, int n)
{
    constexpr int LANES = 16;
    constexpr int FPL   = FEAT / LANES;       // 8 (FEAT=128) or 4 (FEAT=64)
    constexpr int SUBL  = LANES / H;          // lanes per head subgroup
    const int tid = blockIdx.x * 256 + threadIdx.x;
    const int d = tid >> 4;
    if (d >= n) return;
    const int lane = threadIdx.x & (LANES - 1);
    const int myhead = lane / SUBL;
    const int sl = lane % SUBL;
    const int start = off[d], end = off[d + 1];

    const float adm = ad_[d * H + myhead];

    // pass A: online segment max + denom (my head), then subgroup reduce
    float m = -3.4e38f, s = 0.f;
    for (int j = start + sl; j < end; j += SUBL) {
        int sc = csr_src[j];
        float v = as_[sc * H + myhead] + adm;
        v = v > 0.f ? v : 0.2f * v;
        float mn = fmaxf(m, v);
        s = fmaf(s, __expf(m - mn), __expf(v - mn));
        m = mn;
    }
    #pragma unroll
    for (int o = SUBL / 2; o > 0; o >>= 1) {
        float om = __shfl_xor(m, o, 64);
        float os = __shfl_xor(s, o, 64);
        float mn = fmaxf(m, om);
        s = fmaf(s, __expf(m - mn), os * __expf(om - mn));
        m = mn;
    }
    const float inv = 1.f / (s + 1e-16f);

    // pass B: weighted accumulate; all 16 lanes gather their bf16 chunk of each src row
    float acc[FPL];
    #pragma unroll
    for (int k = 0; k < FPL; ++k) acc[k] = 0.f;

    int j = start;
    for (; j + 1 < end; j += 2) {
        int s0 = csr_src[j], s1 = csr_src[j + 1];
        float v0 = as_[s0 * H + myhead] + adm; v0 = v0 > 0.f ? v0 : 0.2f * v0;
        float v1 = as_[s1 * H + myhead] + adm; v1 = v1 > 0.f ? v1 : 0.2f * v1;
        float a0 = __expf(v0 - m) * inv;
        float a1 = __expf(v1 - m) * inv;
        if constexpr (FPL == 8) {
            uint4 r0 = ((const uint4*)(hb + (size_t)s0 * FEAT))[lane];
            uint4 r1 = ((const uint4*)(hb + (size_t)s1 * FEAT))[lane];
            acc[0] = fmaf(blo(r0.x), a0, fmaf(blo(r1.x), a1, acc[0]));
            acc[1] = fmaf(bhi(r0.x), a0, fmaf(bhi(r1.x), a1, acc[1]));
            acc[2] = fmaf(blo(r0.y), a0, fmaf(blo(r1.y), a1, acc[2]));
            acc[3] = fmaf(bhi(r0.y), a0, fmaf(bhi(r1.y), a1, acc[3]));
            acc[4] = fmaf(blo(r0.z), a0, fmaf(blo(r1.z), a1, acc[4]));
            acc[5] = fmaf(bhi(r0.z), a0, fmaf(bhi(r1.z), a1, acc[5]));
            acc[6] = fmaf(blo(r0.w), a0, fmaf(blo(r1.w), a1, acc[6]));
            acc[7] = fmaf(bhi(r0.w), a0, fmaf(bhi(r1.w), a1, acc[7]));
        } else {
            uint2 r0 = ((const uint2*)(hb + (size_t)s0 * FEAT))[lane];
            uint2 r1 = ((const uint2*)(hb + (size_t)s1 * FEAT))[lane];
            acc[0] = fmaf(blo(r0.x), a0, fmaf(blo(r1.x), a1, acc[0]));
            acc[1] = fmaf(bhi(r0.x), a0, fmaf(bhi(r1.x), a1, acc[1]));
            acc[2] = fmaf(blo(r0.y), a0, fmaf(blo(r1.y), a1, acc[2]));
            acc[3] = fmaf(bhi(r0.y), a0, fmaf(bhi(r1.y), a1, acc[3]));
        }
    }
    for (; j < end; ++j) {
        int s0 = csr_src[j];
        float v0 = as_[s0 * H + myhead] + adm; v0 = v0 > 0.f ? v0 : 0.2f * v0;
        float a0 = __expf(v0 - m) * inv;
        if constexpr (FPL == 8) {
            uint4 r0 = ((const uint4*)(hb + (size_t)s0 * FEAT))[lane];
            acc[0] = fmaf(blo(r0.x), a0, acc[0]);
            acc[1] = fmaf(bhi(r0.x), a0, acc[1]);
            acc[2] = fmaf(blo(r0.y), a0, acc[2]);
            acc[3] = fmaf(bhi(r0.y), a0, acc[3]);
            acc[4] = fmaf(blo(r0.z), a0, acc[4]);
            acc[5] = fmaf(bhi(r0.z), a0, acc[5]);
            acc[6] = fmaf(blo(r0.w), a0, acc[6]);
            acc[7] = fmaf(bhi(r0.w), a0, acc[7]);
        } else {
            uint2 r0 = ((const uint2*)(hb + (size_t)s0 * FEAT))[lane];
            acc[0] = fmaf(blo(r0.x), a0, acc[0]);
            acc[1] = fmaf(bhi(r0.x), a0, acc[1]);
            acc[2] = fmaf(blo(r0.y), a0, acc[2]);
            acc[3] = fmaf(bhi(r0.y), a0, acc[3]);
        }
    }

    #pragma unroll
    for (int k = 0; k < FPL; ++k) {
        float o = acc[k] + bias[lane * FPL + k];
        if (ACT == 1) o = fmaxf(o, 0.f);
        out[(size_t)d * FEAT + lane * FPL + k] = o;
    }
}

// ---------------- launch ----------------
extern "C" void kernel_launch(void* const* d_in, const int* in_sizes, int n_in,
                              void* d_out, int out_size, void* d_ws, size_t ws_size,
                              hipStream_t stream)
{
    const int n = in_sizes[0] / 128;     // N nodes
    const int E = in_sizes[1] / 2;       // edges

    const float* x   = (const float*)d_in[0];
    const int*   ei  = (const int*)d_in[1];
    const float* eps = (const float*)d_in[3];
    const float* W1  = (const float*)d_in[4];
    const float* as1w= (const float*)d_in[5];
    const float* ad1w= (const float*)d_in[6];
    const float* b1  = (const float*)d_in[7];
    const float* W2  = (const float*)d_in[8];
    const float* as2w= (const float*)d_in[9];
    const float* ad2w= (const float*)d_in[10];
    const float* b2  = (const float*)d_in[11];
    const float* fc1w= (const float*)d_in[12];
    const float* fc1b= (const float*)d_in[13];
    const float* muw = (const float*)d_in[14];
    const float* mub = (const float*)d_in[15];
    const float* lvw = (const float*)d_in[16];
    const float* lvb = (const float*)d_in[17];
    const float* fc3w= (const float*)d_in[18];
    const float* fc3b= (const float*)d_in[19];
    const float* fc4w= (const float*)d_in[20];
    const float* fc4b= (const float*)d_in[21];

    char* ws = (char*)d_ws;

    size_t oDeg   = 0;
    size_t oOff   = oDeg  + (size_t)n * 4;
    size_t oIncl  = oOff  + (size_t)(n + 1) * 4;
    size_t oCur   = oIncl + (size_t)n * 4;
    size_t oBsum  = oCur  + (size_t)n * 4;
    size_t oCsr   = oBsum + 512 * 4;
    size_t oH1    = oCsr  + (size_t)E * 4;          // region sized f32[n,128]
    size_t oHl2   = oH1   + (size_t)n * 128 * 4;    // f32 [n,128]
    size_t oH2    = oHl2  + (size_t)n * 128 * 4;    // region sized f32[n,64]
    size_t oAS1   = oH2   + (size_t)n * 64 * 4;
    size_t oAD1   = oAS1  + (size_t)n * 2 * 4;
    size_t oAS2   = oAD1  + (size_t)n * 2 * 4;
    size_t oAD2   = oAS2  + (size_t)n * 4;

    int* deg    = (int*)(ws + oDeg);
    int* off    = (int*)(ws + oOff);
    int* incl   = (int*)(ws + oIncl);
    int* cursor = (int*)(ws + oCur);
    int* bsum   = (int*)(ws + oBsum);
    int* csr    = (int*)(ws + oCsr);
    unsigned short* h1b = (unsigned short*)(ws + oH1);   // bf16 [n,128]
    float* hl2  = (float*)(ws + oHl2);
    unsigned short* h2b = (unsigned short*)(ws + oH2);   // bf16 [n,64]
    float* as1  = (float*)(ws + oAS1);
    float* ad1  = (float*)(ws + oAD1);
    float* as2  = (float*)(ws + oAS2);
    float* ad2  = (float*)(ws + oAD2);
    float* h1v  = (float*)(ws + oH1);    // reuse (f32 [n,128], after h1b dead)
    float* h3   = (float*)(ws + oH1);    // reuse
    float* zb   = (float*)(ws + oH2);    // reuse (f32 [n,16], after h2b dead)

    float* out     = (float*)d_out;
    float* o_recon = out;
    float* o_mu    = out + (size_t)n * 64;
    float* o_lv    = out + (size_t)n * 80;
    float* o_gat   = out + (size_t)n * 96;

    const int ebl  = (E + 255) / 256;
    const int nbS  = (n + 255) / 256;
    const int abl  = (n * 16 + 255) / 256;   // 16 lanes per dst
    const int gblk = (n + 127) / 128;

    // --- CSR build ---
    hipMemsetAsync(deg, 0, (size_t)n * 4, stream);
    count_k<<<ebl, 256, 0, stream>>>(ei, deg, E);
    scanA_k<<<nbS, 256, 0, stream>>>(deg, incl, bsum, n);
    scanB_k<<<1, 512, 0, stream>>>(bsum, nbS);
    scanC_k<<<nbS, 256, 0, stream>>>(deg, incl, bsum, off, cursor, n, E);
    scatter_k<<<ebl, 256, 0, stream>>>(ei, cursor, csr, E);

    // --- GAT layer 1 ---
    tgemm_k<128, 128, 32, 0, true><<<gblk, 256, 0, stream>>>(x, W1, nullptr, h1b, n);
    attn_dots_k<2, 64><<<(n * 2 + 255) / 256, 256, 0, stream>>>(h1b, as1w, ad1w, as1, ad1, n);
    gat_agg_k<128, 2, 1><<<abl, 256, 0, stream>>>(csr, off, as1, ad1, h1b, b1, hl2, n);

    // --- GAT layer 2 ---
    tgemm_k<128, 64, 32, 0, true><<<gblk, 256, 0, stream>>>(hl2, W2, nullptr, h2b, n);
    attn_dots_k<1, 64><<<(n + 255) / 256, 256, 0, stream>>>(h2b, as2w, ad2w, as2, ad2, n);
    gat_agg_k<64, 1, 0><<<abl, 256, 0, stream>>>(csr, off, as2, ad2, h2b, b2, o_gat, n);

    // --- VAE ---
    tgemm_k<64, 128, 32, 1, false><<<gblk, 256, 0, stream>>>(o_gat, fc1w, fc1b, h1v, n);
    mulv_k<<<gblk, 256, 0, stream>>>(h1v, muw, lvw, mub, lvb, eps, o_mu, o_lv, zb, n);
    tgemm_k<16, 128, 16, 1, false><<<gblk, 256, 0, stream>>>(zb, fc3w, fc3b, h3, n);
    tgemm_k<128, 64, 32, 0, false><<<gblk, 256, 0, stream>>>(h3, fc4w, fc4b, o_recon, n);
}

// Round 6
// 554.221 us; speedup vs baseline: 5.4241x; 1.0871x over previous
//
#include <hip/hip_runtime.h>
#include <hip/hip_bf16.h>

__device__ __forceinline__ float4 fma4(float s, float4 b, float4 c) {
    c.x = fmaf(s, b.x, c.x); c.y = fmaf(s, b.y, c.y);
    c.z = fmaf(s, b.z, c.z); c.w = fmaf(s, b.w, c.w);
    return c;
}

__device__ __forceinline__ unsigned short f2b_bits(float x) {
    __hip_bfloat16 h = __float2bfloat16(x);
    unsigned short u;
    __builtin_memcpy(&u, &h, 2);
    return u;
}
__device__ __forceinline__ unsigned int pack2(float a, float b) {
    return (unsigned int)f2b_bits(a) | ((unsigned int)f2b_bits(b) << 16);
}
__device__ __forceinline__ float blo(unsigned int u) { return __uint_as_float(u << 16); }
__device__ __forceinline__ float bhi(unsigned int u) { return __uint_as_float(u & 0xffff0000u); }

// ---------------- LDS-tiled node GEMM: out = act(A @ W + bias) ----------------
template<int FIN, int FOUT, int BK, int ACT, bool OBF>
__global__ __launch_bounds__(256) void tgemm_k(const float* __restrict__ A,
                                               const float* __restrict__ W,
                                               const float* __restrict__ bias,
                                               void* __restrict__ outv, int n)
{
    constexpr int BM  = 128;
    constexpr int BMp = BM + 4;
    constexpr int NT_N = FOUT / 4;
    constexpr int NT_M = 256 / NT_N;
    constexpr int RG   = (BM / NT_M) / 4;
    __shared__ __align__(16) float As[BK * BMp];
    __shared__ __align__(16) float Bs[BK * FOUT];

    const int t  = threadIdx.x;
    const int m0 = blockIdx.x * BM;
    const int tn = t % NT_N, tm = t / NT_N;

    float4 acc[RG][4];
    #pragma unroll
    for (int g = 0; g < RG; ++g)
        #pragma unroll
        for (int i = 0; i < 4; ++i) acc[g][i] = make_float4(0.f, 0.f, 0.f, 0.f);

    for (int kt = 0; kt < FIN; kt += BK) {
        __syncthreads();
        #pragma unroll
        for (int idx = t; idx < BM * BK / 4; idx += 256) {
            int r  = idx / (BK / 4);
            int c4 = (idx % (BK / 4)) * 4;
            int row = m0 + r;
            float4 v = make_float4(0.f, 0.f, 0.f, 0.f);
            if (row < n) v = *(const float4*)(A + (size_t)row * FIN + kt + c4);
            As[(c4 + 0) * BMp + r] = v.x;
            As[(c4 + 1) * BMp + r] = v.y;
            As[(c4 + 2) * BMp + r] = v.z;
            As[(c4 + 3) * BMp + r] = v.w;
        }
        #pragma unroll
        for (int idx = t; idx < BK * FOUT / 4; idx += 256) {
            int kr = idx / (FOUT / 4);
            int c4 = (idx % (FOUT / 4)) * 4;
            *(float4*)(Bs + kr * FOUT + c4) =
                *(const float4*)(W + (size_t)(kt + kr) * FOUT + c4);
        }
        __syncthreads();
        #pragma unroll 8
        for (int k = 0; k < BK; ++k) {
            float4 b = *(const float4*)(Bs + k * FOUT + 4 * tn);
            #pragma unroll
            for (int g = 0; g < RG; ++g) {
                float4 a = *(const float4*)(As + k * BMp + 4 * (tm + NT_M * g));
                acc[g][0] = fma4(a.x, b, acc[g][0]);
                acc[g][1] = fma4(a.y, b, acc[g][1]);
                acc[g][2] = fma4(a.z, b, acc[g][2]);
                acc[g][3] = fma4(a.w, b, acc[g][3]);
            }
        }
    }

    float4 bb = make_float4(0.f, 0.f, 0.f, 0.f);
    if (bias) bb = *(const float4*)(bias + 4 * tn);
    #pragma unroll
    for (int g = 0; g < RG; ++g)
        #pragma unroll
        for (int i = 0; i < 4; ++i) {
            int row = m0 + 4 * (tm + NT_M * g) + i;
            if (row < n) {
                float4 o = acc[g][i];
                o.x += bb.x; o.y += bb.y; o.z += bb.z; o.w += bb.w;
                if (ACT == 1) {
                    o.x = fmaxf(o.x, 0.f); o.y = fmaxf(o.y, 0.f);
                    o.z = fmaxf(o.z, 0.f); o.w = fmaxf(o.w, 0.f);
                }
                if constexpr (OBF) {
                    unsigned short* outb = (unsigned short*)outv;
                    uint2 pv = make_uint2(pack2(o.x, o.y), pack2(o.z, o.w));
                    *(uint2*)(outb + (size_t)row * FOUT + 4 * tn) = pv;
                } else {
                    float* outf = (float*)outv;
                    *(float4*)(outf + (size_t)row * FOUT + 4 * tn) = o;
                }
            }
        }
}

// ---------------- fused mu/logvar GEMM + reparameterize ----------------
__global__ __launch_bounds__(256) void mulv_k(const float* __restrict__ A,
                                              const float* __restrict__ muw,
                                              const float* __restrict__ lvw,
                                              const float* __restrict__ mub,
                                              const float* __restrict__ lvb,
                                              const float* __restrict__ eps,
                                              float* __restrict__ o_mu,
                                              float* __restrict__ o_lv,
                                              float* __restrict__ zb, int n)
{
    constexpr int FIN = 128, BK = 32, BN = 32;
    constexpr int BM = 128, BMp = BM + 4;
    constexpr int NT_N = BN / 4;      // 8
    __shared__ __align__(16) float As[BK * BMp];
    __shared__ __align__(16) float Bs[BK * BN];

    const int t  = threadIdx.x;
    const int m0 = blockIdx.x * BM;
    const int tn = t % NT_N, tm = t / NT_N;

    float4 acc[4];
    #pragma unroll
    for (int i = 0; i < 4; ++i) acc[i] = make_float4(0.f, 0.f, 0.f, 0.f);

    for (int kt = 0; kt < FIN; kt += BK) {
        __syncthreads();
        #pragma unroll
        for (int idx = t; idx < BM * BK / 4; idx += 256) {
            int r  = idx / (BK / 4);
            int c4 = (idx % (BK / 4)) * 4;
            int row = m0 + r;
            float4 v = make_float4(0.f, 0.f, 0.f, 0.f);
            if (row < n) v = *(const float4*)(A + (size_t)row * FIN + kt + c4);
            As[(c4 + 0) * BMp + r] = v.x;
            As[(c4 + 1) * BMp + r] = v.y;
            As[(c4 + 2) * BMp + r] = v.z;
            As[(c4 + 3) * BMp + r] = v.w;
        }
        {
            int kr = t / 8, c4 = (t % 8) * 4;
            const float* src = (c4 < 16) ? (muw + (size_t)(kt + kr) * 16 + c4)
                                         : (lvw + (size_t)(kt + kr) * 16 + (c4 - 16));
            *(float4*)(Bs + kr * BN + c4) = *(const float4*)src;
        }
        __syncthreads();
        #pragma unroll 8
        for (int k = 0; k < BK; ++k) {
            float4 b = *(const float4*)(Bs + k * BN + 4 * tn);
            float4 a = *(const float4*)(As + k * BMp + 4 * tm);
            acc[0] = fma4(a.x, b, acc[0]);
            acc[1] = fma4(a.y, b, acc[1]);
            acc[2] = fma4(a.z, b, acc[2]);
            acc[3] = fma4(a.w, b, acc[3]);
        }
    }

    const bool is_mu = (tn < 4);
    const int  c16   = is_mu ? 4 * tn : 4 * tn - 16;
    float4 bb = is_mu ? *(const float4*)(mub + c16) : *(const float4*)(lvb + c16);

    #pragma unroll
    for (int i = 0; i < 4; ++i) {
        int row = m0 + 4 * tm + i;
        float4 v = acc[i];
        v.x += bb.x; v.y += bb.y; v.z += bb.z; v.w += bb.w;
        float4 lvx;
        lvx.x = __shfl_xor(v.x, 4, 64);
        lvx.y = __shfl_xor(v.y, 4, 64);
        lvx.z = __shfl_xor(v.z, 4, 64);
        lvx.w = __shfl_xor(v.w, 4, 64);
        if (row < n) {
            if (is_mu) {
                *(float4*)(o_mu + (size_t)row * 16 + c16) = v;
                float4 ep = *(const float4*)(eps + (size_t)row * 16 + c16);
                float4 z;
                z.x = fmaf(ep.x, __expf(0.5f * fminf(fmaxf(lvx.x, -10.f), 10.f)), v.x);
                z.y = fmaf(ep.y, __expf(0.5f * fminf(fmaxf(lvx.y, -10.f), 10.f)), v.y);
                z.z = fmaf(ep.z, __expf(0.5f * fminf(fmaxf(lvx.z, -10.f), 10.f)), v.z);
                z.w = fmaf(ep.w, __expf(0.5f * fminf(fmaxf(lvx.w, -10.f), 10.f)), v.w);
                *(float4*)(zb + (size_t)row * 16 + c16) = z;
            } else {
                *(float4*)(o_lv + (size_t)row * 16 + c16) = v;
            }
        }
    }
}

// ---------------- per-node attention dot products (bf16 h) ----------------
template<int H, int D>
__global__ __launch_bounds__(256) void attn_dots_k(const unsigned short* __restrict__ h,
                                                   const float* __restrict__ asr,
                                                   const float* __restrict__ adr,
                                                   float* __restrict__ as_o,
                                                   float* __restrict__ ad_o, int n)
{
    int t = blockIdx.x * 256 + threadIdx.x;
    if (t >= n * H) return;
    int node = t / H, hd = t - node * H;
    const uint4* row = (const uint4*)(h + (size_t)node * (H * D) + hd * D);
    const float* av = asr + hd * D;
    const float* bv = adr + hd * D;
    float ds = 0.f, dd = 0.f;
    #pragma unroll 1
    for (int k8 = 0; k8 < D; k8 += 8) {
        uint4 r = row[k8 >> 3];
        float v[8] = { blo(r.x), bhi(r.x), blo(r.y), bhi(r.y),
                       blo(r.z), bhi(r.z), blo(r.w), bhi(r.w) };
        #pragma unroll
        for (int u = 0; u < 8; ++u) {
            ds = fmaf(v[u], av[k8 + u], ds);
            dd = fmaf(v[u], bv[k8 + u], dd);
        }
    }
    as_o[t] = ds;
    ad_o[t] = dd;
}

// ---------------- CSR build ----------------
__global__ __launch_bounds__(256) void count_k(const int* __restrict__ ei, int* __restrict__ deg, int E)
{
    int e = blockIdx.x * 256 + threadIdx.x;
    if (e >= E) return;
    atomicAdd(&deg[ei[E + e]], 1);
}

__global__ __launch_bounds__(256) void scanA_k(const int* __restrict__ deg, int* __restrict__ incl,
                                               int* __restrict__ bsum, int n)
{
    __shared__ int sh[256];
    int i = blockIdx.x * 256 + threadIdx.x;
    int v = (i < n) ? deg[i] : 0;
    sh[threadIdx.x] = v;
    __syncthreads();
    #pragma unroll
    for (int o = 1; o < 256; o <<= 1) {
        int t = (threadIdx.x >= o) ? sh[threadIdx.x - o] : 0;
        __syncthreads();
        sh[threadIdx.x] += t;
        __syncthreads();
    }
    if (i < n) incl[i] = sh[threadIdx.x];
    if (threadIdx.x == 255) bsum[blockIdx.x] = sh[255];
}

__global__ __launch_bounds__(512) void scanB_k(int* __restrict__ bsum, int nb)
{
    __shared__ int sh[512];
    int v = (threadIdx.x < nb) ? bsum[threadIdx.x] : 0;
    sh[threadIdx.x] = v;
    __syncthreads();
    #pragma unroll
    for (int o = 1; o < 512; o <<= 1) {
        int t = (threadIdx.x >= o) ? sh[threadIdx.x - o] : 0;
        __syncthreads();
        sh[threadIdx.x] += t;
        __syncthreads();
    }
    if (threadIdx.x < nb) bsum[threadIdx.x] = sh[threadIdx.x] - v;
}

__global__ __launch_bounds__(256) void scanC_k(const int* __restrict__ deg, const int* __restrict__ incl,
                                               const int* __restrict__ bsum, int* __restrict__ off,
                                               int* __restrict__ cursor, int n, int E)
{
    int i = blockIdx.x * 256 + threadIdx.x;
    if (i >= n) return;
    int v = incl[i] - deg[i] + bsum[i >> 8];
    off[i] = v;
    cursor[i] = v;
    if (i == 0) off[n] = E;
}

// dst-range-partitioned scatter: group g = blockIdx&7 (≈XCD) owns dst range g.
// All csr lines of a range are written from one XCD's L2 -> lines fill before
// write-back -> ~6.4 MB instead of 16x-amplified 102 MB. ei dst column is
// L3-resident (read by count_k), so the 8x re-read is cheap.
__global__ __launch_bounds__(256) void scatter_k(const int* __restrict__ ei, int* __restrict__ cursor,
                                                 int* __restrict__ csr_src, int E, int n)
{
    const int grp = blockIdx.x & 7;
    const int bin = blockIdx.x >> 3;
    const int bpg = gridDim.x >> 3;
    const int rsz = (n + 7) >> 3;
    const int lo = grp * rsz;
    const int hi = min(n, lo + rsz);
    const int stride = bpg * 256;
    for (int e = bin * 256 + threadIdx.x; e < E; e += stride) {
        int d = ei[E + e];
        if (d >= lo && d < hi) {
            int pos = atomicAdd(&cursor[d], 1);
            csr_src[pos] = ei[e];
        }
    }
}

// ---------------- fused per-dst softmax + aggregate ----------------
template<int FEAT, int H, int ACT>
__global__ __launch_bounds__(256) void gat_agg_k(const int* __restrict__ csr_src,
                                                 const int* __restrict__ off,
                                                 const float* __restrict__ as_,
                                                 const float* __restrict__ ad_,
                                                 const unsigned short* __restrict__ hb,
                                                 const float* __restrict__ bias,
                                                 float* __restrict__ out, int n)
{
    constexpr int LANES = 16;
    constexpr int FPL   = FEAT / LANES;
    constexpr int SUBL  = LANES / H;
    const int tid = blockIdx.x * 256 + threadIdx.x;
    const int d = tid >> 4;
    if (d >= n) return;
    const int lane = threadIdx.x & (LANES - 1);
    const int myhead = lane / SUBL;
    const int sl = lane % SUBL;
    const int start = off[d], end = off[d + 1];

    const float adm = ad_[d * H + myhead];

    float m = -3.4e38f, s = 0.f;
    for (int j = start + sl; j < end; j += SUBL) {
        int sc = csr_src[j];
        float v = as_[sc * H + myhead] + adm;
        v = v > 0.f ? v : 0.2f * v;
        float mn = fmaxf(m, v);
        s = fmaf(s, __expf(m - mn), __expf(v - mn));
        m = mn;
    }
    #pragma unroll
    for (int o = SUBL / 2; o > 0; o >>= 1) {
        float om = __shfl_xor(m, o, 64);
        float os = __shfl_xor(s, o, 64);
        float mn = fmaxf(m, om);
        s = fmaf(s, __expf(m - mn), os * __expf(om - mn));
        m = mn;
    }
    const float inv = 1.f / (s + 1e-16f);

    float acc[FPL];
    #pragma unroll
    for (int k = 0; k < FPL; ++k) acc[k] = 0.f;

    int j = start;
    for (; j + 1 < end; j += 2) {
        int s0 = csr_src[j], s1 = csr_src[j + 1];
        float v0 = as_[s0 * H + myhead] + adm; v0 = v0 > 0.f ? v0 : 0.2f * v0;
        float v1 = as_[s1 * H + myhead] + adm; v1 = v1 > 0.f ? v1 : 0.2f * v1;
        float a0 = __expf(v0 - m) * inv;
        float a1 = __expf(v1 - m) * inv;
        if constexpr (FPL == 8) {
            uint4 r0 = ((const uint4*)(hb + (size_t)s0 * FEAT))[lane];
            uint4 r1 = ((const uint4*)(hb + (size_t)s1 * FEAT))[lane];
            acc[0] = fmaf(blo(r0.x), a0, fmaf(blo(r1.x), a1, acc[0]));
            acc[1] = fmaf(bhi(r0.x), a0, fmaf(bhi(r1.x), a1, acc[1]));
            acc[2] = fmaf(blo(r0.y), a0, fmaf(blo(r1.y), a1, acc[2]));
            acc[3] = fmaf(bhi(r0.y), a0, fmaf(bhi(r1.y), a1, acc[3]));
            acc[4] = fmaf(blo(r0.z), a0, fmaf(blo(r1.z), a1, acc[4]));
            acc[5] = fmaf(bhi(r0.z), a0, fmaf(bhi(r1.z), a1, acc[5]));
            acc[6] = fmaf(blo(r0.w), a0, fmaf(blo(r1.w), a1, acc[6]));
            acc[7] = fmaf(bhi(r0.w), a0, fmaf(bhi(r1.w), a1, acc[7]));
        } else {
            uint2 r0 = ((const uint2*)(hb + (size_t)s0 * FEAT))[lane];
            uint2 r1 = ((const uint2*)(hb + (size_t)s1 * FEAT))[lane];
            acc[0] = fmaf(blo(r0.x), a0, fmaf(blo(r1.x), a1, acc[0]));
            acc[1] = fmaf(bhi(r0.x), a0, fmaf(bhi(r1.x), a1, acc[1]));
            acc[2] = fmaf(blo(r0.y), a0, fmaf(blo(r1.y), a1, acc[2]));
            acc[3] = fmaf(bhi(r0.y), a0, fmaf(bhi(r1.y), a1, acc[3]));
        }
    }
    for (; j < end; ++j) {
        int s0 = csr_src[j];
        float v0 = as_[s0 * H + myhead] + adm; v0 = v0 > 0.f ? v0 : 0.2f * v0;
        float a0 = __expf(v0 - m) * inv;
        if constexpr (FPL == 8) {
            uint4 r0 = ((const uint4*)(hb + (size_t)s0 * FEAT))[lane];
            acc[0] = fmaf(blo(r0.x), a0, acc[0]);
            acc[1] = fmaf(bhi(r0.x), a0, acc[1]);
            acc[2] = fmaf(blo(r0.y), a0, acc[2]);
            acc[3] = fmaf(bhi(r0.y), a0, acc[3]);
            acc[4] = fmaf(blo(r0.z), a0, acc[4]);
            acc[5] = fmaf(bhi(r0.z), a0, acc[5]);
            acc[6] = fmaf(blo(r0.w), a0, acc[6]);
            acc[7] = fmaf(bhi(r0.w), a0, acc[7]);
        } else {
            uint2 r0 = ((const uint2*)(hb + (size_t)s0 * FEAT))[lane];
            acc[0] = fmaf(blo(r0.x), a0, acc[0]);
            acc[1] = fmaf(bhi(r0.x), a0, acc[1]);
            acc[2] = fmaf(blo(r0.y), a0, acc[2]);
            acc[3] = fmaf(bhi(r0.y), a0, acc[3]);
        }
    }

    #pragma unroll
    for (int k = 0; k < FPL; ++k) {
        float o = acc[k] + bias[lane * FPL + k];
        if (ACT == 1) o = fmaxf(o, 0.f);
        out[(size_t)d * FEAT + lane * FPL + k] = o;
    }
}

// ---------------- launch ----------------
extern "C" void kernel_launch(void* const* d_in, const int* in_sizes, int n_in,
                              void* d_out, int out_size, void* d_ws, size_t ws_size,
                              hipStream_t stream)
{
    const int n = in_sizes[0] / 128;     // N nodes
    const int E = in_sizes[1] / 2;       // edges

    const float* x   = (const float*)d_in[0];
    const int*   ei  = (const int*)d_in[1];
    const float* eps = (const float*)d_in[3];
    const float* W1  = (const float*)d_in[4];
    const float* as1w= (const float*)d_in[5];
    const float* ad1w= (const float*)d_in[6];
    const float* b1  = (const float*)d_in[7];
    const float* W2  = (const float*)d_in[8];
    const float* as2w= (const float*)d_in[9];
    const float* ad2w= (const float*)d_in[10];
    const float* b2  = (const float*)d_in[11];
    const float* fc1w= (const float*)d_in[12];
    const float* fc1b= (const float*)d_in[13];
    const float* muw = (const float*)d_in[14];
    const float* mub = (const float*)d_in[15];
    const float* lvw = (const float*)d_in[16];
    const float* lvb = (const float*)d_in[17];
    const float* fc3w= (const float*)d_in[18];
    const float* fc3b= (const float*)d_in[19];
    const float* fc4w= (const float*)d_in[20];
    const float* fc4b= (const float*)d_in[21];

    char* ws = (char*)d_ws;

    size_t oDeg   = 0;
    size_t oOff   = oDeg  + (size_t)n * 4;
    size_t oIncl  = oOff  + (size_t)(n + 1) * 4;
    size_t oCur   = oIncl + (size_t)n * 4;
    size_t oBsum  = oCur  + (size_t)n * 4;
    size_t oCsr   = oBsum + 512 * 4;
    size_t oH1    = oCsr  + (size_t)E * 4;
    size_t oHl2   = oH1   + (size_t)n * 128 * 4;
    size_t oH2    = oHl2  + (size_t)n * 128 * 4;
    size_t oAS1   = oH2   + (size_t)n * 64 * 4;
    size_t oAD1   = oAS1  + (size_t)n * 2 * 4;
    size_t oAS2   = oAD1  + (size_t)n * 2 * 4;
    size_t oAD2   = oAS2  + (size_t)n * 4;

    int* deg    = (int*)(ws + oDeg);
    int* off    = (int*)(ws + oOff);
    int* incl   = (int*)(ws + oIncl);
    int* cursor = (int*)(ws + oCur);
    int* bsum   = (int*)(ws + oBsum);
    int* csr    = (int*)(ws + oCsr);
    unsigned short* h1b = (unsigned short*)(ws + oH1);   // bf16 [n,128]
    float* hl2  = (float*)(ws + oHl2);
    unsigned short* h2b = (unsigned short*)(ws + oH2);   // bf16 [n,64]
    float* as1  = (float*)(ws + oAS1);
    float* ad1  = (float*)(ws + oAD1);
    float* as2  = (float*)(ws + oAS2);
    float* ad2  = (float*)(ws + oAD2);
    float* h1v  = (float*)(ws + oH1);    // reuse
    float* h3   = (float*)(ws + oH1);    // reuse
    float* zb   = (float*)(ws + oH2);    // reuse

    float* out     = (float*)d_out;
    float* o_recon = out;
    float* o_mu    = out + (size_t)n * 64;
    float* o_lv    = out + (size_t)n * 80;
    float* o_gat   = out + (size_t)n * 96;

    const int ebl  = (E + 255) / 256;
    const int nbS  = (n + 255) / 256;
    const int abl  = (n * 16 + 255) / 256;
    const int gblk = (n + 127) / 128;

    // --- CSR build ---
    hipMemsetAsync(deg, 0, (size_t)n * 4, stream);
    count_k<<<ebl, 256, 0, stream>>>(ei, deg, E);
    scanA_k<<<nbS, 256, 0, stream>>>(deg, incl, bsum, n);
    scanB_k<<<1, 512, 0, stream>>>(bsum, nbS);
    scanC_k<<<nbS, 256, 0, stream>>>(deg, incl, bsum, off, cursor, n, E);
    scatter_k<<<1024, 256, 0, stream>>>(ei, cursor, csr, E, n);

    // --- GAT layer 1 ---
    tgemm_k<128, 128, 32, 0, true><<<gblk, 256, 0, stream>>>(x, W1, nullptr, h1b, n);
    attn_dots_k<2, 64><<<(n * 2 + 255) / 256, 256, 0, stream>>>(h1b, as1w, ad1w, as1, ad1, n);
    gat_agg_k<128, 2, 1><<<abl, 256, 0, stream>>>(csr, off, as1, ad1, h1b, b1, hl2, n);

    // --- GAT layer 2 ---
    tgemm_k<128, 64, 32, 0, true><<<gblk, 256, 0, stream>>>(hl2, W2, nullptr, h2b, n);
    attn_dots_k<1, 64><<<(n + 255) / 256, 256, 0, stream>>>(h2b, as2w, ad2w, as2, ad2, n);
    gat_agg_k<64, 1, 0><<<abl, 256, 0, stream>>>(csr, off, as2, ad2, h2b, b2, o_gat, n);

    // --- VAE ---
    tgemm_k<64, 128, 32, 1, false><<<gblk, 256, 0, stream>>>(o_gat, fc1w, fc1b, h1v, n);
    mulv_k<<<gblk, 256, 0, stream>>>(h1v, muw, lvw, mub, lvb, eps, o_mu, o_lv, zb, n);
    tgemm_k<16, 128, 16, 1, false><<<gblk, 256, 0, stream>>>(zb, fc3w, fc3b, h3, n);
    tgemm_k<128, 64, 32, 0, false><<<gblk, 256, 0, stream>>>(h3, fc4w, fc4b, o_recon, n);
}

// Round 7
// 540.281 us; speedup vs baseline: 5.5641x; 1.0258x over previous
//
#include <hip/hip_runtime.h>
#include <hip/hip_bf16.h>

__device__ __forceinline__ float4 fma4(float s, float4 b, float4 c) {
    c.x = fmaf(s, b.x, c.x); c.y = fmaf(s, b.y, c.y);
    c.z = fmaf(s, b.z, c.z); c.w = fmaf(s, b.w, c.w);
    return c;
}

__device__ __forceinline__ unsigned short f2b_bits(float x) {
    __hip_bfloat16 h = __float2bfloat16(x);
    unsigned short u;
    __builtin_memcpy(&u, &h, 2);
    return u;
}
__device__ __forceinline__ unsigned int pack2(float a, float b) {
    return (unsigned int)f2b_bits(a) | ((unsigned int)f2b_bits(b) << 16);
}
__device__ __forceinline__ float blo(unsigned int u) { return __uint_as_float(u << 16); }
__device__ __forceinline__ float bhi(unsigned int u) { return __uint_as_float(u & 0xffff0000u); }

// ---------------- LDS-tiled node GEMM: out = act(A @ W + bias) ----------------
// HD > 0: also emit attention dots (aso/ado[row*HD+head]) from pre-bias acc.
template<int FIN, int FOUT, int BK, int ACT, bool OBF, int HD>
__global__ __launch_bounds__(256) void tgemm_k(const float* __restrict__ A,
                                               const float* __restrict__ W,
                                               const float* __restrict__ bias,
                                               void* __restrict__ outv,
                                               const float* __restrict__ asr,
                                               const float* __restrict__ adr,
                                               float* __restrict__ aso,
                                               float* __restrict__ ado, int n)
{
    constexpr int BM  = 128;
    constexpr int BMp = BM + 4;
    constexpr int NT_N = FOUT / 4;
    constexpr int NT_M = 256 / NT_N;
    constexpr int RG   = (BM / NT_M) / 4;
    __shared__ __align__(16) float As[BK * BMp];
    __shared__ __align__(16) float Bs[BK * FOUT];

    const int t  = threadIdx.x;
    const int m0 = blockIdx.x * BM;
    const int tn = t % NT_N, tm = t / NT_N;

    float4 acc[RG][4];
    #pragma unroll
    for (int g = 0; g < RG; ++g)
        #pragma unroll
        for (int i = 0; i < 4; ++i) acc[g][i] = make_float4(0.f, 0.f, 0.f, 0.f);

    for (int kt = 0; kt < FIN; kt += BK) {
        __syncthreads();
        #pragma unroll
        for (int idx = t; idx < BM * BK / 4; idx += 256) {
            int r  = idx / (BK / 4);
            int c4 = (idx % (BK / 4)) * 4;
            int row = m0 + r;
            float4 v = make_float4(0.f, 0.f, 0.f, 0.f);
            if (row < n) v = *(const float4*)(A + (size_t)row * FIN + kt + c4);
            As[(c4 + 0) * BMp + r] = v.x;
            As[(c4 + 1) * BMp + r] = v.y;
            As[(c4 + 2) * BMp + r] = v.z;
            As[(c4 + 3) * BMp + r] = v.w;
        }
        #pragma unroll
        for (int idx = t; idx < BK * FOUT / 4; idx += 256) {
            int kr = idx / (FOUT / 4);
            int c4 = (idx % (FOUT / 4)) * 4;
            *(float4*)(Bs + kr * FOUT + c4) =
                *(const float4*)(W + (size_t)(kt + kr) * FOUT + c4);
        }
        __syncthreads();
        #pragma unroll 8
        for (int k = 0; k < BK; ++k) {
            float4 b = *(const float4*)(Bs + k * FOUT + 4 * tn);
            #pragma unroll
            for (int g = 0; g < RG; ++g) {
                float4 a = *(const float4*)(As + k * BMp + 4 * (tm + NT_M * g));
                acc[g][0] = fma4(a.x, b, acc[g][0]);
                acc[g][1] = fma4(a.y, b, acc[g][1]);
                acc[g][2] = fma4(a.z, b, acc[g][2]);
                acc[g][3] = fma4(a.w, b, acc[g][3]);
            }
        }
    }

    // ---- fused attention dots (pre-bias values; GAT layers pass bias=null, ACT=0) ----
    if constexpr (HD > 0) {
        float4 av = *(const float4*)(asr + 4 * tn);
        float4 dv = *(const float4*)(adr + 4 * tn);
        const int head = tn / (NT_N / HD);
        #pragma unroll
        for (int g = 0; g < RG; ++g)
            #pragma unroll
            for (int i = 0; i < 4; ++i) {
                float4 o = acc[g][i];
                float ds = fmaf(o.x, av.x, fmaf(o.y, av.y, fmaf(o.z, av.z, o.w * av.w)));
                float dd = fmaf(o.x, dv.x, fmaf(o.y, dv.y, fmaf(o.z, dv.z, o.w * dv.w)));
                #pragma unroll
                for (int off = 8; off > 0; off >>= 1) {
                    ds += __shfl_xor(ds, off, 16);
                    dd += __shfl_xor(dd, off, 16);
                }
                if ((tn & 15) == 0) {
                    int row = m0 + 4 * (tm + NT_M * g) + i;
                    if (row < n) {
                        aso[(size_t)row * HD + head] = ds;
                        ado[(size_t)row * HD + head] = dd;
                    }
                }
            }
    }

    float4 bb = make_float4(0.f, 0.f, 0.f, 0.f);
    if (bias) bb = *(const float4*)(bias + 4 * tn);
    #pragma unroll
    for (int g = 0; g < RG; ++g)
        #pragma unroll
        for (int i = 0; i < 4; ++i) {
            int row = m0 + 4 * (tm + NT_M * g) + i;
            if (row < n) {
                float4 o = acc[g][i];
                o.x += bb.x; o.y += bb.y; o.z += bb.z; o.w += bb.w;
                if (ACT == 1) {
                    o.x = fmaxf(o.x, 0.f); o.y = fmaxf(o.y, 0.f);
                    o.z = fmaxf(o.z, 0.f); o.w = fmaxf(o.w, 0.f);
                }
                if constexpr (OBF) {
                    unsigned short* outb = (unsigned short*)outv;
                    uint2 pv = make_uint2(pack2(o.x, o.y), pack2(o.z, o.w));
                    *(uint2*)(outb + (size_t)row * FOUT + 4 * tn) = pv;
                } else {
                    float* outf = (float*)outv;
                    *(float4*)(outf + (size_t)row * FOUT + 4 * tn) = o;
                }
            }
        }
}

// ---------------- fused mu/logvar GEMM + reparameterize ----------------
__global__ __launch_bounds__(256) void mulv_k(const float* __restrict__ A,
                                              const float* __restrict__ muw,
                                              const float* __restrict__ lvw,
                                              const float* __restrict__ mub,
                                              const float* __restrict__ lvb,
                                              const float* __restrict__ eps,
                                              float* __restrict__ o_mu,
                                              float* __restrict__ o_lv,
                                              float* __restrict__ zb, int n)
{
    constexpr int FIN = 128, BK = 32, BN = 32;
    constexpr int BM = 128, BMp = BM + 4;
    constexpr int NT_N = BN / 4;      // 8
    __shared__ __align__(16) float As[BK * BMp];
    __shared__ __align__(16) float Bs[BK * BN];

    const int t  = threadIdx.x;
    const int m0 = blockIdx.x * BM;
    const int tn = t % NT_N, tm = t / NT_N;

    float4 acc[4];
    #pragma unroll
    for (int i = 0; i < 4; ++i) acc[i] = make_float4(0.f, 0.f, 0.f, 0.f);

    for (int kt = 0; kt < FIN; kt += BK) {
        __syncthreads();
        #pragma unroll
        for (int idx = t; idx < BM * BK / 4; idx += 256) {
            int r  = idx / (BK / 4);
            int c4 = (idx % (BK / 4)) * 4;
            int row = m0 + r;
            float4 v = make_float4(0.f, 0.f, 0.f, 0.f);
            if (row < n) v = *(const float4*)(A + (size_t)row * FIN + kt + c4);
            As[(c4 + 0) * BMp + r] = v.x;
            As[(c4 + 1) * BMp + r] = v.y;
            As[(c4 + 2) * BMp + r] = v.z;
            As[(c4 + 3) * BMp + r] = v.w;
        }
        {
            int kr = t / 8, c4 = (t % 8) * 4;
            const float* src = (c4 < 16) ? (muw + (size_t)(kt + kr) * 16 + c4)
                                         : (lvw + (size_t)(kt + kr) * 16 + (c4 - 16));
            *(float4*)(Bs + kr * BN + c4) = *(const float4*)src;
        }
        __syncthreads();
        #pragma unroll 8
        for (int k = 0; k < BK; ++k) {
            float4 b = *(const float4*)(Bs + k * BN + 4 * tn);
            float4 a = *(const float4*)(As + k * BMp + 4 * tm);
            acc[0] = fma4(a.x, b, acc[0]);
            acc[1] = fma4(a.y, b, acc[1]);
            acc[2] = fma4(a.z, b, acc[2]);
            acc[3] = fma4(a.w, b, acc[3]);
        }
    }

    const bool is_mu = (tn < 4);
    const int  c16   = is_mu ? 4 * tn : 4 * tn - 16;
    float4 bb = is_mu ? *(const float4*)(mub + c16) : *(const float4*)(lvb + c16);

    #pragma unroll
    for (int i = 0; i < 4; ++i) {
        int row = m0 + 4 * tm + i;
        float4 v = acc[i];
        v.x += bb.x; v.y += bb.y; v.z += bb.z; v.w += bb.w;
        float4 lvx;
        lvx.x = __shfl_xor(v.x, 4, 64);
        lvx.y = __shfl_xor(v.y, 4, 64);
        lvx.z = __shfl_xor(v.z, 4, 64);
        lvx.w = __shfl_xor(v.w, 4, 64);
        if (row < n) {
            if (is_mu) {
                *(float4*)(o_mu + (size_t)row * 16 + c16) = v;
                float4 ep = *(const float4*)(eps + (size_t)row * 16 + c16);
                float4 z;
                z.x = fmaf(ep.x, __expf(0.5f * fminf(fmaxf(lvx.x, -10.f), 10.f)), v.x);
                z.y = fmaf(ep.y, __expf(0.5f * fminf(fmaxf(lvx.y, -10.f), 10.f)), v.y);
                z.z = fmaf(ep.z, __expf(0.5f * fminf(fmaxf(lvx.z, -10.f), 10.f)), v.z);
                z.w = fmaf(ep.w, __expf(0.5f * fminf(fmaxf(lvx.w, -10.f), 10.f)), v.w);
                *(float4*)(zb + (size_t)row * 16 + c16) = z;
            } else {
                *(float4*)(o_lv + (size_t)row * 16 + c16) = v;
            }
        }
    }
}

// ---------------- CSR build ----------------
__global__ __launch_bounds__(256) void count_k(const int* __restrict__ ei, int* __restrict__ deg, int E)
{
    int e = blockIdx.x * 256 + threadIdx.x;
    if (e >= E) return;
    atomicAdd(&deg[ei[E + e]], 1);
}

__global__ __launch_bounds__(256) void scanA_k(const int* __restrict__ deg, int* __restrict__ incl,
                                               int* __restrict__ bsum, int n)
{
    __shared__ int sh[256];
    int i = blockIdx.x * 256 + threadIdx.x;
    int v = (i < n) ? deg[i] : 0;
    sh[threadIdx.x] = v;
    __syncthreads();
    #pragma unroll
    for (int o = 1; o < 256; o <<= 1) {
        int t = (threadIdx.x >= o) ? sh[threadIdx.x - o] : 0;
        __syncthreads();
        sh[threadIdx.x] += t;
        __syncthreads();
    }
    if (i < n) incl[i] = sh[threadIdx.x];
    if (threadIdx.x == 255) bsum[blockIdx.x] = sh[255];
}

__global__ __launch_bounds__(512) void scanB_k(int* __restrict__ bsum, int nb)
{
    __shared__ int sh[512];
    int v = (threadIdx.x < nb) ? bsum[threadIdx.x] : 0;
    sh[threadIdx.x] = v;
    __syncthreads();
    #pragma unroll
    for (int o = 1; o < 512; o <<= 1) {
        int t = (threadIdx.x >= o) ? sh[threadIdx.x - o] : 0;
        __syncthreads();
        sh[threadIdx.x] += t;
        __syncthreads();
    }
    if (threadIdx.x < nb) bsum[threadIdx.x] = sh[threadIdx.x] - v;
}

__global__ __launch_bounds__(256) void scanC_k(const int* __restrict__ deg, const int* __restrict__ incl,
                                               const int* __restrict__ bsum, int* __restrict__ off,
                                               int* __restrict__ cursor, int n, int E)
{
    int i = blockIdx.x * 256 + threadIdx.x;
    if (i >= n) return;
    int v = incl[i] - deg[i] + bsum[i >> 8];
    off[i] = v;
    cursor[i] = v;
    if (i == 0) off[n] = E;
}

// dst-range-partitioned scatter (write-combining in one XCD's L2 per range)
__global__ __launch_bounds__(256) void scatter_k(const int* __restrict__ ei, int* __restrict__ cursor,
                                                 int* __restrict__ csr_src, int E, int n)
{
    const int grp = blockIdx.x & 7;
    const int bin = blockIdx.x >> 3;
    const int bpg = gridDim.x >> 3;
    const int rsz = (n + 7) >> 3;
    const int lo = grp * rsz;
    const int hi = min(n, lo + rsz);
    const int stride = bpg * 256;
    for (int e = bin * 256 + threadIdx.x; e < E; e += stride) {
        int d = ei[E + e];
        if (d >= lo && d < hi) {
            int pos = atomicAdd(&cursor[d], 1);
            csr_src[pos] = ei[e];
        }
    }
}

// ---------------- fused per-dst softmax + aggregate ----------------
// 16 lanes per dst; pass A caches v/src in regs (<=4 chunks fast path);
// pass B broadcasts alpha/src via shfl -> 1 exp per (edge,head), 8/16-deep gather MLP.
template<int FEAT, int H, int ACT>
__global__ __launch_bounds__(256) void gat_agg_k(const int* __restrict__ csr_src,
                                                 const int* __restrict__ off,
                                                 const float* __restrict__ as_,
                                                 const float* __restrict__ ad_,
                                                 const unsigned short* __restrict__ hb,
                                                 const float* __restrict__ bias,
                                                 float* __restrict__ out, int n)
{
    constexpr int LANES = 16;
    constexpr int FPL   = FEAT / LANES;   // 8 or 4
    constexpr int SUBL  = LANES / H;      // 8 (H=2) or 16 (H=1)
    constexpr int NCH   = 4;              // register-cached chunks
    const int tid = blockIdx.x * 256 + threadIdx.x;
    const int d = tid >> 4;
    if (d >= n) return;
    const int lane = threadIdx.x & 15;
    const int myhead = lane / SUBL;
    const int sl = lane % SUBL;
    const int start = off[d], end = off[d + 1];
    const float adm = ad_[d * H + myhead];

    // pass A: load & cache v/src, track max
    float vreg[NCH]; int sreg[NCH];
    float m = -3.4e38f;
    #pragma unroll
    for (int c = 0; c < NCH; ++c) {
        int j = start + sl + c * SUBL;
        int s = 0; float v = -3.4e38f;
        if (j < end) {
            s = csr_src[j];
            v = as_[s * H + myhead] + adm;
            v = v > 0.f ? v : 0.2f * v;
        }
        sreg[c] = s; vreg[c] = v;
        m = fmaxf(m, v);
    }
    for (int j = start + sl + NCH * SUBL; j < end; j += SUBL) {   // rare overflow
        int s = csr_src[j];
        float v = as_[s * H + myhead] + adm;
        v = v > 0.f ? v : 0.2f * v;
        m = fmaxf(m, v);
    }
    #pragma unroll
    for (int o = SUBL / 2; o > 0; o >>= 1)
        m = fmaxf(m, __shfl_xor(m, o, SUBL));

    float ssum = 0.f;
    #pragma unroll
    for (int c = 0; c < NCH; ++c)
        if (start + sl + c * SUBL < end) ssum += __expf(vreg[c] - m);
    for (int j = start + sl + NCH * SUBL; j < end; j += SUBL) {
        int s = csr_src[j];
        float v = as_[s * H + myhead] + adm;
        v = v > 0.f ? v : 0.2f * v;
        ssum += __expf(v - m);
    }
    #pragma unroll
    for (int o = SUBL / 2; o > 0; o >>= 1)
        ssum += __shfl_xor(ssum, o, SUBL);
    const float inv = 1.f / (ssum + 1e-16f);

    // pass B: chunked gather with shfl-broadcast alpha/src
    float acc[FPL];
    #pragma unroll
    for (int k = 0; k < FPL; ++k) acc[k] = 0.f;

    auto body = [&](float a, int s) {
        if constexpr (FPL == 8) {
            uint4 r = ((const uint4*)(hb + (size_t)s * FEAT))[lane];
            acc[0] = fmaf(blo(r.x), a, acc[0]);
            acc[1] = fmaf(bhi(r.x), a, acc[1]);
            acc[2] = fmaf(blo(r.y), a, acc[2]);
            acc[3] = fmaf(bhi(r.y), a, acc[3]);
            acc[4] = fmaf(blo(r.z), a, acc[4]);
            acc[5] = fmaf(bhi(r.z), a, acc[5]);
            acc[6] = fmaf(blo(r.w), a, acc[6]);
            acc[7] = fmaf(bhi(r.w), a, acc[7]);
        } else {
            uint2 r = ((const uint2*)(hb + (size_t)s * FEAT))[lane];
            acc[0] = fmaf(blo(r.x), a, acc[0]);
            acc[1] = fmaf(bhi(r.x), a, acc[1]);
            acc[2] = fmaf(blo(r.y), a, acc[2]);
            acc[3] = fmaf(bhi(r.y), a, acc[3]);
        }
    };

    const int nch = (end - start + SUBL - 1) / SUBL;
    for (int c = 0; c < nch; ++c) {
        const int j0 = start + c * SUBL;
        const int cnt = min(SUBL, end - j0);
        float myalpha = 0.f; int mysrc = 0;
        if (c < NCH) {
            mysrc = sreg[c];
            if (sl < cnt) myalpha = __expf(vreg[c] - m) * inv;
        } else {
            if (sl < cnt) {
                mysrc = csr_src[j0 + sl];
                float v = as_[mysrc * H + myhead] + adm;
                v = v > 0.f ? v : 0.2f * v;
                myalpha = __expf(v - m) * inv;
            }
        }
        if (cnt == SUBL) {
            #pragma unroll
            for (int u = 0; u < SUBL; ++u) {
                float a = __shfl(myalpha, myhead * SUBL + u, LANES);
                int   s = __shfl(mysrc, u, LANES);
                body(a, s);
            }
        } else {
            for (int u = 0; u < cnt; ++u) {
                float a = __shfl(myalpha, myhead * SUBL + u, LANES);
                int   s = __shfl(mysrc, u, LANES);
                body(a, s);
            }
        }
    }

    #pragma unroll
    for (int k = 0; k < FPL; ++k) {
        float o = acc[k] + bias[lane * FPL + k];
        if (ACT == 1) o = fmaxf(o, 0.f);
        out[(size_t)d * FEAT + lane * FPL + k] = o;
    }
}

// ---------------- launch ----------------
extern "C" void kernel_launch(void* const* d_in, const int* in_sizes, int n_in,
                              void* d_out, int out_size, void* d_ws, size_t ws_size,
                              hipStream_t stream)
{
    const int n = in_sizes[0] / 128;     // N nodes
    const int E = in_sizes[1] / 2;       // edges

    const float* x   = (const float*)d_in[0];
    const int*   ei  = (const int*)d_in[1];
    const float* eps = (const float*)d_in[3];
    const float* W1  = (const float*)d_in[4];
    const float* as1w= (const float*)d_in[5];
    const float* ad1w= (const float*)d_in[6];
    const float* b1  = (const float*)d_in[7];
    const float* W2  = (const float*)d_in[8];
    const float* as2w= (const float*)d_in[9];
    const float* ad2w= (const float*)d_in[10];
    const float* b2  = (const float*)d_in[11];
    const float* fc1w= (const float*)d_in[12];
    const float* fc1b= (const float*)d_in[13];
    const float* muw = (const float*)d_in[14];
    const float* mub = (const float*)d_in[15];
    const float* lvw = (const float*)d_in[16];
    const float* lvb = (const float*)d_in[17];
    const float* fc3w= (const float*)d_in[18];
    const float* fc3b= (const float*)d_in[19];
    const float* fc4w= (const float*)d_in[20];
    const float* fc4b= (const float*)d_in[21];

    char* ws = (char*)d_ws;

    size_t oDeg   = 0;
    size_t oOff   = oDeg  + (size_t)n * 4;
    size_t oIncl  = oOff  + (size_t)(n + 1) * 4;
    size_t oCur   = oIncl + (size_t)n * 4;
    size_t oBsum  = oCur  + (size_t)n * 4;
    size_t oCsr   = oBsum + 512 * 4;
    size_t oH1    = oCsr  + (size_t)E * 4;
    size_t oHl2   = oH1   + (size_t)n * 128 * 4;
    size_t oH2    = oHl2  + (size_t)n * 128 * 4;
    size_t oAS1   = oH2   + (size_t)n * 64 * 4;
    size_t oAD1   = oAS1  + (size_t)n * 2 * 4;
    size_t oAS2   = oAD1  + (size_t)n * 2 * 4;
    size_t oAD2   = oAS2  + (size_t)n * 4;

    int* deg    = (int*)(ws + oDeg);
    int* off    = (int*)(ws + oOff);
    int* incl   = (int*)(ws + oIncl);
    int* cursor = (int*)(ws + oCur);
    int* bsum   = (int*)(ws + oBsum);
    int* csr    = (int*)(ws + oCsr);
    unsigned short* h1b = (unsigned short*)(ws + oH1);   // bf16 [n,128]
    float* hl2  = (float*)(ws + oHl2);
    unsigned short* h2b = (unsigned short*)(ws + oH2);   // bf16 [n,64]
    float* as1  = (float*)(ws + oAS1);
    float* ad1  = (float*)(ws + oAD1);
    float* as2  = (float*)(ws + oAS2);
    float* ad2  = (float*)(ws + oAD2);
    float* h1v  = (float*)(ws + oH1);    // reuse
    float* h3   = (float*)(ws + oH1);    // reuse
    float* zb   = (float*)(ws + oH2);    // reuse

    float* out     = (float*)d_out;
    float* o_recon = out;
    float* o_mu    = out + (size_t)n * 64;
    float* o_lv    = out + (size_t)n * 80;
    float* o_gat   = out + (size_t)n * 96;

    const int ebl  = (E + 255) / 256;
    const int nbS  = (n + 255) / 256;
    const int abl  = (n * 16 + 255) / 256;
    const int gblk = (n + 127) / 128;

    // --- CSR build ---
    hipMemsetAsync(deg, 0, (size_t)n * 4, stream);
    count_k<<<ebl, 256, 0, stream>>>(ei, deg, E);
    scanA_k<<<nbS, 256, 0, stream>>>(deg, incl, bsum, n);
    scanB_k<<<1, 512, 0, stream>>>(bsum, nbS);
    scanC_k<<<nbS, 256, 0, stream>>>(deg, incl, bsum, off, cursor, n, E);
    scatter_k<<<1024, 256, 0, stream>>>(ei, cursor, csr, E, n);

    // --- GAT layer 1 (dots fused into GEMM epilogue) ---
    tgemm_k<128, 128, 32, 0, true, 2><<<gblk, 256, 0, stream>>>(
        x, W1, nullptr, h1b, as1w, ad1w, as1, ad1, n);
    gat_agg_k<128, 2, 1><<<abl, 256, 0, stream>>>(csr, off, as1, ad1, h1b, b1, hl2, n);

    // --- GAT layer 2 ---
    tgemm_k<128, 64, 32, 0, true, 1><<<gblk, 256, 0, stream>>>(
        hl2, W2, nullptr, h2b, as2w, ad2w, as2, ad2, n);
    gat_agg_k<64, 1, 0><<<abl, 256, 0, stream>>>(csr, off, as2, ad2, h2b, b2, o_gat, n);

    // --- VAE ---
    tgemm_k<64, 128, 32, 1, false, 0><<<gblk, 256, 0, stream>>>(
        o_gat, fc1w, fc1b, h1v, nullptr, nullptr, nullptr, nullptr, n);
    mulv_k<<<gblk, 256, 0, stream>>>(h1v, muw, lvw, mub, lvb, eps, o_mu, o_lv, zb, n);
    tgemm_k<16, 128, 16, 1, false, 0><<<gblk, 256, 0, stream>>>(
        zb, fc3w, fc3b, h3, nullptr, nullptr, nullptr, nullptr, n);
    tgemm_k<128, 64, 32, 0, false, 0><<<gblk, 256, 0, stream>>>(
        h3, fc4w, fc4b, o_recon, nullptr, nullptr, nullptr, nullptr, n);
}

// Round 8
// 525.932 us; speedup vs baseline: 5.7159x; 1.0273x over previous
//
#include <hip/hip_runtime.h>
#include <hip/hip_bf16.h>

__device__ __forceinline__ float4 fma4(float s, float4 b, float4 c) {
    c.x = fmaf(s, b.x, c.x); c.y = fmaf(s, b.y, c.y);
    c.z = fmaf(s, b.z, c.z); c.w = fmaf(s, b.w, c.w);
    return c;
}

__device__ __forceinline__ unsigned short f2b_bits(float x) {
    __hip_bfloat16 h = __float2bfloat16(x);
    unsigned short u;
    __builtin_memcpy(&u, &h, 2);
    return u;
}
__device__ __forceinline__ unsigned int pack2(float a, float b) {
    return (unsigned int)f2b_bits(a) | ((unsigned int)f2b_bits(b) << 16);
}
__device__ __forceinline__ float blo(unsigned int u) { return __uint_as_float(u << 16); }
__device__ __forceinline__ float bhi(unsigned int u) { return __uint_as_float(u & 0xffff0000u); }
__device__ __forceinline__ float sx8(unsigned int w, int b) {   // signed byte b of w
    return (float)((int)(w << (24 - 8 * b)) >> 24);
}

// ---------------- LDS-tiled node GEMM ----------------
// OUTK: 0=f32, 1=bf16, 2=int8 row-quant (+scales). ABF: A is bf16.
// HD>0: emit attention dots from f32 acc (pre-quant).
template<int FIN, int FOUT, int BK, int ACT, int OUTK, bool ABF, int HD>
__global__ __launch_bounds__(256) void tgemm_k(const void* __restrict__ Av,
                                               const float* __restrict__ W,
                                               const float* __restrict__ bias,
                                               void* __restrict__ outv,
                                               float* __restrict__ scales,
                                               const float* __restrict__ asr,
                                               const float* __restrict__ adr,
                                               float* __restrict__ aso,
                                               float* __restrict__ ado, int n)
{
    constexpr int BM  = 128;
    constexpr int BMp = BM + 4;
    constexpr int NT_N = FOUT / 4;
    constexpr int NT_M = 256 / NT_N;
    constexpr int RG   = (BM / NT_M) / 4;
    __shared__ __align__(16) float As[BK * BMp];
    __shared__ __align__(16) float Bs[BK * FOUT];

    const float* Af = (const float*)Av;
    const unsigned short* Ab = (const unsigned short*)Av;

    const int t  = threadIdx.x;
    const int m0 = blockIdx.x * BM;
    const int tn = t % NT_N, tm = t / NT_N;

    float4 acc[RG][4];
    #pragma unroll
    for (int g = 0; g < RG; ++g)
        #pragma unroll
        for (int i = 0; i < 4; ++i) acc[g][i] = make_float4(0.f, 0.f, 0.f, 0.f);

    for (int kt = 0; kt < FIN; kt += BK) {
        __syncthreads();
        #pragma unroll
        for (int idx = t; idx < BM * BK / 4; idx += 256) {
            int r  = idx / (BK / 4);
            int c4 = (idx % (BK / 4)) * 4;
            int row = m0 + r;
            float4 v = make_float4(0.f, 0.f, 0.f, 0.f);
            if (row < n) {
                if constexpr (ABF) {
                    uint2 rv = *(const uint2*)(Ab + (size_t)row * FIN + kt + c4);
                    v = make_float4(blo(rv.x), bhi(rv.x), blo(rv.y), bhi(rv.y));
                } else {
                    v = *(const float4*)(Af + (size_t)row * FIN + kt + c4);
                }
            }
            As[(c4 + 0) * BMp + r] = v.x;
            As[(c4 + 1) * BMp + r] = v.y;
            As[(c4 + 2) * BMp + r] = v.z;
            As[(c4 + 3) * BMp + r] = v.w;
        }
        #pragma unroll
        for (int idx = t; idx < BK * FOUT / 4; idx += 256) {
            int kr = idx / (FOUT / 4);
            int c4 = (idx % (FOUT / 4)) * 4;
            *(float4*)(Bs + kr * FOUT + c4) =
                *(const float4*)(W + (size_t)(kt + kr) * FOUT + c4);
        }
        __syncthreads();
        #pragma unroll 8
        for (int k = 0; k < BK; ++k) {
            float4 b = *(const float4*)(Bs + k * FOUT + 4 * tn);
            #pragma unroll
            for (int g = 0; g < RG; ++g) {
                float4 a = *(const float4*)(As + k * BMp + 4 * (tm + NT_M * g));
                acc[g][0] = fma4(a.x, b, acc[g][0]);
                acc[g][1] = fma4(a.y, b, acc[g][1]);
                acc[g][2] = fma4(a.z, b, acc[g][2]);
                acc[g][3] = fma4(a.w, b, acc[g][3]);
            }
        }
    }

    if constexpr (HD > 0) {
        float4 av = *(const float4*)(asr + 4 * tn);
        float4 dv = *(const float4*)(adr + 4 * tn);
        const int head = tn / (NT_N / HD);
        #pragma unroll
        for (int g = 0; g < RG; ++g)
            #pragma unroll
            for (int i = 0; i < 4; ++i) {
                float4 o = acc[g][i];
                float ds = fmaf(o.x, av.x, fmaf(o.y, av.y, fmaf(o.z, av.z, o.w * av.w)));
                float dd = fmaf(o.x, dv.x, fmaf(o.y, dv.y, fmaf(o.z, dv.z, o.w * dv.w)));
                #pragma unroll
                for (int off = 8; off > 0; off >>= 1) {
                    ds += __shfl_xor(ds, off, 16);
                    dd += __shfl_xor(dd, off, 16);
                }
                if ((tn & 15) == 0) {
                    int row = m0 + 4 * (tm + NT_M * g) + i;
                    if (row < n) {
                        aso[(size_t)row * HD + head] = ds;
                        ado[(size_t)row * HD + head] = dd;
                    }
                }
            }
    }

    float4 bb = make_float4(0.f, 0.f, 0.f, 0.f);
    if (bias) bb = *(const float4*)(bias + 4 * tn);
    #pragma unroll
    for (int g = 0; g < RG; ++g)
        #pragma unroll
        for (int i = 0; i < 4; ++i) {
            int row = m0 + 4 * (tm + NT_M * g) + i;
            if (row < n) {
                float4 o = acc[g][i];
                if constexpr (OUTK == 2) {
                    // per-row symmetric int8 quant (bias/ACT unused on this path)
                    float amax = fmaxf(fmaxf(fabsf(o.x), fabsf(o.y)),
                                       fmaxf(fabsf(o.z), fabsf(o.w)));
                    #pragma unroll
                    for (int off = NT_N / 2; off > 0; off >>= 1)
                        amax = fmaxf(amax, __shfl_xor(amax, off, NT_N));
                    float invsc = amax > 0.f ? 127.f / amax : 0.f;
                    int q0 = __float2int_rn(o.x * invsc);
                    int q1 = __float2int_rn(o.y * invsc);
                    int q2 = __float2int_rn(o.z * invsc);
                    int q3 = __float2int_rn(o.w * invsc);
                    unsigned int pv = (q0 & 255) | ((q1 & 255) << 8) |
                                      ((q2 & 255) << 16) | ((q3 & 255) << 24);
                    ((unsigned int*)outv)[(size_t)row * (FOUT / 4) + tn] = pv;
                    if (tn == 0) scales[row] = amax * (1.f / 127.f);
                } else {
                    o.x += bb.x; o.y += bb.y; o.z += bb.z; o.w += bb.w;
                    if (ACT == 1) {
                        o.x = fmaxf(o.x, 0.f); o.y = fmaxf(o.y, 0.f);
                        o.z = fmaxf(o.z, 0.f); o.w = fmaxf(o.w, 0.f);
                    }
                    if constexpr (OUTK == 1) {
                        unsigned short* outb = (unsigned short*)outv;
                        uint2 pv = make_uint2(pack2(o.x, o.y), pack2(o.z, o.w));
                        *(uint2*)(outb + (size_t)row * FOUT + 4 * tn) = pv;
                    } else {
                        float* outf = (float*)outv;
                        *(float4*)(outf + (size_t)row * FOUT + 4 * tn) = o;
                    }
                }
            }
        }
}

// ---------------- fused mu/logvar GEMM + reparameterize ----------------
__global__ __launch_bounds__(256) void mulv_k(const float* __restrict__ A,
                                              const float* __restrict__ muw,
                                              const float* __restrict__ lvw,
                                              const float* __restrict__ mub,
                                              const float* __restrict__ lvb,
                                              const float* __restrict__ eps,
                                              float* __restrict__ o_mu,
                                              float* __restrict__ o_lv,
                                              float* __restrict__ zb, int n)
{
    constexpr int FIN = 128, BK = 32, BN = 32;
    constexpr int BM = 128, BMp = BM + 4;
    constexpr int NT_N = BN / 4;      // 8
    __shared__ __align__(16) float As[BK * BMp];
    __shared__ __align__(16) float Bs[BK * BN];

    const int t  = threadIdx.x;
    const int m0 = blockIdx.x * BM;
    const int tn = t % NT_N, tm = t / NT_N;

    float4 acc[4];
    #pragma unroll
    for (int i = 0; i < 4; ++i) acc[i] = make_float4(0.f, 0.f, 0.f, 0.f);

    for (int kt = 0; kt < FIN; kt += BK) {
        __syncthreads();
        #pragma unroll
        for (int idx = t; idx < BM * BK / 4; idx += 256) {
            int r  = idx / (BK / 4);
            int c4 = (idx % (BK / 4)) * 4;
            int row = m0 + r;
            float4 v = make_float4(0.f, 0.f, 0.f, 0.f);
            if (row < n) v = *(const float4*)(A + (size_t)row * FIN + kt + c4);
            As[(c4 + 0) * BMp + r] = v.x;
            As[(c4 + 1) * BMp + r] = v.y;
            As[(c4 + 2) * BMp + r] = v.z;
            As[(c4 + 3) * BMp + r] = v.w;
        }
        {
            int kr = t / 8, c4 = (t % 8) * 4;
            const float* src = (c4 < 16) ? (muw + (size_t)(kt + kr) * 16 + c4)
                                         : (lvw + (size_t)(kt + kr) * 16 + (c4 - 16));
            *(float4*)(Bs + kr * BN + c4) = *(const float4*)src;
        }
        __syncthreads();
        #pragma unroll 8
        for (int k = 0; k < BK; ++k) {
            float4 b = *(const float4*)(Bs + k * BN + 4 * tn);
            float4 a = *(const float4*)(As + k * BMp + 4 * tm);
            acc[0] = fma4(a.x, b, acc[0]);
            acc[1] = fma4(a.y, b, acc[1]);
            acc[2] = fma4(a.z, b, acc[2]);
            acc[3] = fma4(a.w, b, acc[3]);
        }
    }

    const bool is_mu = (tn < 4);
    const int  c16   = is_mu ? 4 * tn : 4 * tn - 16;
    float4 bb = is_mu ? *(const float4*)(mub + c16) : *(const float4*)(lvb + c16);

    #pragma unroll
    for (int i = 0; i < 4; ++i) {
        int row = m0 + 4 * tm + i;
        float4 v = acc[i];
        v.x += bb.x; v.y += bb.y; v.z += bb.z; v.w += bb.w;
        float4 lvx;
        lvx.x = __shfl_xor(v.x, 4, 64);
        lvx.y = __shfl_xor(v.y, 4, 64);
        lvx.z = __shfl_xor(v.z, 4, 64);
        lvx.w = __shfl_xor(v.w, 4, 64);
        if (row < n) {
            if (is_mu) {
                *(float4*)(o_mu + (size_t)row * 16 + c16) = v;
                float4 ep = *(const float4*)(eps + (size_t)row * 16 + c16);
                float4 z;
                z.x = fmaf(ep.x, __expf(0.5f * fminf(fmaxf(lvx.x, -10.f), 10.f)), v.x);
                z.y = fmaf(ep.y, __expf(0.5f * fminf(fmaxf(lvx.y, -10.f), 10.f)), v.y);
                z.z = fmaf(ep.z, __expf(0.5f * fminf(fmaxf(lvx.z, -10.f), 10.f)), v.z);
                z.w = fmaf(ep.w, __expf(0.5f * fminf(fmaxf(lvx.w, -10.f), 10.f)), v.w);
                *(float4*)(zb + (size_t)row * 16 + c16) = z;
            } else {
                *(float4*)(o_lv + (size_t)row * 16 + c16) = v;
            }
        }
    }
}

// ---------------- CSR build ----------------
__global__ __launch_bounds__(256) void count_k(const int* __restrict__ ei, int* __restrict__ deg, int E)
{
    int e = blockIdx.x * 256 + threadIdx.x;
    if (e >= E) return;
    atomicAdd(&deg[ei[E + e]], 1);
}

__global__ __launch_bounds__(256) void scanA_k(const int* __restrict__ deg, int* __restrict__ incl,
                                               int* __restrict__ bsum, int n)
{
    __shared__ int sh[256];
    int i = blockIdx.x * 256 + threadIdx.x;
    int v = (i < n) ? deg[i] : 0;
    sh[threadIdx.x] = v;
    __syncthreads();
    #pragma unroll
    for (int o = 1; o < 256; o <<= 1) {
        int t = (threadIdx.x >= o) ? sh[threadIdx.x - o] : 0;
        __syncthreads();
        sh[threadIdx.x] += t;
        __syncthreads();
    }
    if (i < n) incl[i] = sh[threadIdx.x];
    if (threadIdx.x == 255) bsum[blockIdx.x] = sh[255];
}

__global__ __launch_bounds__(512) void scanB_k(int* __restrict__ bsum, int nb)
{
    __shared__ int sh[512];
    int v = (threadIdx.x < nb) ? bsum[threadIdx.x] : 0;
    sh[threadIdx.x] = v;
    __syncthreads();
    #pragma unroll
    for (int o = 1; o < 512; o <<= 1) {
        int t = (threadIdx.x >= o) ? sh[threadIdx.x - o] : 0;
        __syncthreads();
        sh[threadIdx.x] += t;
        __syncthreads();
    }
    if (threadIdx.x < nb) bsum[threadIdx.x] = sh[threadIdx.x] - v;
}

__global__ __launch_bounds__(256) void scanC_k(const int* __restrict__ deg, const int* __restrict__ incl,
                                               const int* __restrict__ bsum, int* __restrict__ off,
                                               int* __restrict__ cursor, int n, int E)
{
    int i = blockIdx.x * 256 + threadIdx.x;
    if (i >= n) return;
    int v = incl[i] - deg[i] + bsum[i >> 8];
    off[i] = v;
    cursor[i] = v;
    if (i == 0) off[n] = E;
}

// dst-range-partitioned scatter (write-combining within one XCD's L2 per range)
__global__ __launch_bounds__(256) void scatter_k(const int* __restrict__ ei, int* __restrict__ cursor,
                                                 int* __restrict__ csr_src, int E, int n)
{
    const int grp = blockIdx.x & 7;
    const int bin = blockIdx.x >> 3;
    const int bpg = gridDim.x >> 3;
    const int rsz = (n + 7) >> 3;
    const int lo = grp * rsz;
    const int hi = min(n, lo + rsz);
    const int stride = bpg * 256;
    for (int e = bin * 256 + threadIdx.x; e < E; e += stride) {
        int d = ei[E + e];
        if (d >= lo && d < hi) {
            int pos = atomicAdd(&cursor[d], 1);
            csr_src[pos] = ei[e];
        }
    }
}

// ---------------- fused per-dst softmax + aggregate (int8 h, scale folded into alpha) ----------------
template<int FEAT, int H, int ACT, bool OUTB>
__global__ __launch_bounds__(256) void gat_agg_k(const int* __restrict__ csr_src,
                                                 const int* __restrict__ off,
                                                 const float* __restrict__ as_,
                                                 const float* __restrict__ ad_,
                                                 const unsigned int* __restrict__ h8,
                                                 const float* __restrict__ sc,
                                                 const float* __restrict__ bias,
                                                 void* __restrict__ outv, int n)
{
    constexpr int LANES = 16;
    constexpr int FPL   = FEAT / LANES;   // 8 or 4
    constexpr int WPR   = FEAT / 4;       // uint words per row
    constexpr int SUBL  = LANES / H;
    constexpr int NCH   = 4;
    const int tid = blockIdx.x * 256 + threadIdx.x;
    const int d = tid >> 4;
    if (d >= n) return;
    const int lane = threadIdx.x & 15;
    const int myhead = lane / SUBL;
    const int sl = lane % SUBL;
    const int start = off[d], end = off[d + 1];
    const float adm = ad_[d * H + myhead];

    // pass A: cache src/v/scale, track max
    float vreg[NCH], sreg_sc[NCH]; int sreg[NCH];
    float m = -3.4e38f;
    #pragma unroll
    for (int c = 0; c < NCH; ++c) {
        int j = start + sl + c * SUBL;
        int s = 0; float v = -3.4e38f, scl = 0.f;
        if (j < end) {
            s = csr_src[j];
            v = as_[s * H + myhead] + adm;
            v = v > 0.f ? v : 0.2f * v;
            scl = sc[s];
        }
        sreg[c] = s; vreg[c] = v; sreg_sc[c] = scl;
        m = fmaxf(m, v);
    }
    for (int j = start + sl + NCH * SUBL; j < end; j += SUBL) {
        int s = csr_src[j];
        float v = as_[s * H + myhead] + adm;
        v = v > 0.f ? v : 0.2f * v;
        m = fmaxf(m, v);
    }
    #pragma unroll
    for (int o = SUBL / 2; o > 0; o >>= 1)
        m = fmaxf(m, __shfl_xor(m, o, SUBL));

    float ssum = 0.f;
    #pragma unroll
    for (int c = 0; c < NCH; ++c)
        if (start + sl + c * SUBL < end) ssum += __expf(vreg[c] - m);
    for (int j = start + sl + NCH * SUBL; j < end; j += SUBL) {
        int s = csr_src[j];
        float v = as_[s * H + myhead] + adm;
        v = v > 0.f ? v : 0.2f * v;
        ssum += __expf(v - m);
    }
    #pragma unroll
    for (int o = SUBL / 2; o > 0; o >>= 1)
        ssum += __shfl_xor(ssum, o, SUBL);
    const float inv = 1.f / (ssum + 1e-16f);

    // pass B: chunked int8 gather, alpha (incl. row scale) broadcast via shfl
    float acc[FPL];
    #pragma unroll
    for (int k = 0; k < FPL; ++k) acc[k] = 0.f;

    auto body = [&](float a, int s) {
        if constexpr (FPL == 8) {
            uint2 r = ((const uint2*)(h8 + (size_t)s * WPR))[lane];
            acc[0] = fmaf(sx8(r.x, 0), a, acc[0]);
            acc[1] = fmaf(sx8(r.x, 1), a, acc[1]);
            acc[2] = fmaf(sx8(r.x, 2), a, acc[2]);
            acc[3] = fmaf(sx8(r.x, 3), a, acc[3]);
            acc[4] = fmaf(sx8(r.y, 0), a, acc[4]);
            acc[5] = fmaf(sx8(r.y, 1), a, acc[5]);
            acc[6] = fmaf(sx8(r.y, 2), a, acc[6]);
            acc[7] = fmaf(sx8(r.y, 3), a, acc[7]);
        } else {
            unsigned int r = (h8 + (size_t)s * WPR)[lane];
            acc[0] = fmaf(sx8(r, 0), a, acc[0]);
            acc[1] = fmaf(sx8(r, 1), a, acc[1]);
            acc[2] = fmaf(sx8(r, 2), a, acc[2]);
            acc[3] = fmaf(sx8(r, 3), a, acc[3]);
        }
    };

    const int nch = (end - start + SUBL - 1) / SUBL;
    for (int c = 0; c < nch; ++c) {
        const int j0 = start + c * SUBL;
        const int cnt = min(SUBL, end - j0);
        float myalpha = 0.f; int mysrc = 0;
        if (c < NCH) {
            mysrc = sreg[c];
            if (sl < cnt) myalpha = __expf(vreg[c] - m) * inv * sreg_sc[c];
        } else {
            if (sl < cnt) {
                mysrc = csr_src[j0 + sl];
                float v = as_[mysrc * H + myhead] + adm;
                v = v > 0.f ? v : 0.2f * v;
                myalpha = __expf(v - m) * inv * sc[mysrc];
            }
        }
        if (cnt == SUBL) {
            #pragma unroll
            for (int u = 0; u < SUBL; ++u) {
                float a = __shfl(myalpha, myhead * SUBL + u, LANES);
                int   s = __shfl(mysrc, u, LANES);
                body(a, s);
            }
        } else {
            for (int u = 0; u < cnt; ++u) {
                float a = __shfl(myalpha, myhead * SUBL + u, LANES);
                int   s = __shfl(mysrc, u, LANES);
                body(a, s);
            }
        }
    }

    if constexpr (OUTB) {   // bf16 out (FPL==8 path)
        float o[FPL];
        #pragma unroll
        for (int k = 0; k < FPL; ++k) {
            o[k] = acc[k] + bias[lane * FPL + k];
            if (ACT == 1) o[k] = fmaxf(o[k], 0.f);
        }
        uint4 pv;
        pv.x = pack2(o[0], o[1]); pv.y = pack2(o[2], o[3]);
        pv.z = pack2(o[4], o[5]); pv.w = pack2(o[6], o[7]);
        *(uint4*)((unsigned short*)outv + (size_t)d * FEAT + lane * FPL) = pv;
    } else {
        float* outf = (float*)outv;
        #pragma unroll
        for (int k = 0; k < FPL; ++k) {
            float o = acc[k] + bias[lane * FPL + k];
            if (ACT == 1) o = fmaxf(o, 0.f);
            outf[(size_t)d * FEAT + lane * FPL + k] = o;
        }
    }
}

// ---------------- launch ----------------
extern "C" void kernel_launch(void* const* d_in, const int* in_sizes, int n_in,
                              void* d_out, int out_size, void* d_ws, size_t ws_size,
                              hipStream_t stream)
{
    const int n = in_sizes[0] / 128;     // N nodes
    const int E = in_sizes[1] / 2;       // edges

    const float* x   = (const float*)d_in[0];
    const int*   ei  = (const int*)d_in[1];
    const float* eps = (const float*)d_in[3];
    const float* W1  = (const float*)d_in[4];
    const float* as1w= (const float*)d_in[5];
    const float* ad1w= (const float*)d_in[6];
    const float* b1  = (const float*)d_in[7];
    const float* W2  = (const float*)d_in[8];
    const float* as2w= (const float*)d_in[9];
    const float* ad2w= (const float*)d_in[10];
    const float* b2  = (const float*)d_in[11];
    const float* fc1w= (const float*)d_in[12];
    const float* fc1b= (const float*)d_in[13];
    const float* muw = (const float*)d_in[14];
    const float* mub = (const float*)d_in[15];
    const float* lvw = (const float*)d_in[16];
    const float* lvb = (const float*)d_in[17];
    const float* fc3w= (const float*)d_in[18];
    const float* fc3b= (const float*)d_in[19];
    const float* fc4w= (const float*)d_in[20];
    const float* fc4b= (const float*)d_in[21];

    char* ws = (char*)d_ws;

    size_t oDeg   = 0;
    size_t oOff   = oDeg  + (size_t)n * 4;
    size_t oIncl  = oOff  + (size_t)(n + 1) * 4;
    size_t oCur   = oIncl + (size_t)n * 4;
    size_t oBsum  = oCur  + (size_t)n * 4;
    size_t oCsr   = oBsum + 512 * 4;
    size_t oH1    = oCsr  + (size_t)E * 4;          // int8[n,128] now; later f32[n,128] h1v/h3
    size_t oHl2   = oH1   + (size_t)n * 128 * 4;    // bf16 [n,128]
    size_t oH2    = oHl2  + (size_t)n * 128 * 4;    // int8[n,64] now; later f32[n,16] zb
    size_t oAS1   = oH2   + (size_t)n * 64 * 4;
    size_t oAD1   = oAS1  + (size_t)n * 2 * 4;
    size_t oAS2   = oAD1  + (size_t)n * 2 * 4;
    size_t oAD2   = oAS2  + (size_t)n * 4;
    size_t oSC1   = oAD2  + (size_t)n * 4;          // f32 [n]
    size_t oSC2   = oSC1  + (size_t)n * 4;          // f32 [n]

    int* deg    = (int*)(ws + oDeg);
    int* off    = (int*)(ws + oOff);
    int* incl   = (int*)(ws + oIncl);
    int* cursor = (int*)(ws + oCur);
    int* bsum   = (int*)(ws + oBsum);
    int* csr    = (int*)(ws + oCsr);
    unsigned int* h1q = (unsigned int*)(ws + oH1);
    unsigned short* hl2b = (unsigned short*)(ws + oHl2);
    unsigned int* h2q = (unsigned int*)(ws + oH2);
    float* as1  = (float*)(ws + oAS1);
    float* ad1  = (float*)(ws + oAD1);
    float* as2  = (float*)(ws + oAS2);
    float* ad2  = (float*)(ws + oAD2);
    float* sc1  = (float*)(ws + oSC1);
    float* sc2  = (float*)(ws + oSC2);
    float* h1v  = (float*)(ws + oH1);    // reuse after h1q dead
    float* h3   = (float*)(ws + oH1);    // reuse
    float* zb   = (float*)(ws + oH2);    // reuse after h2q dead

    float* out     = (float*)d_out;
    float* o_recon = out;
    float* o_mu    = out + (size_t)n * 64;
    float* o_lv    = out + (size_t)n * 80;
    float* o_gat   = out + (size_t)n * 96;

    const int ebl  = (E + 255) / 256;
    const int nbS  = (n + 255) / 256;
    const int abl  = (n * 16 + 255) / 256;
    const int gblk = (n + 127) / 128;

    // --- CSR build ---
    hipMemsetAsync(deg, 0, (size_t)n * 4, stream);
    count_k<<<ebl, 256, 0, stream>>>(ei, deg, E);
    scanA_k<<<nbS, 256, 0, stream>>>(deg, incl, bsum, n);
    scanB_k<<<1, 512, 0, stream>>>(bsum, nbS);
    scanC_k<<<nbS, 256, 0, stream>>>(deg, incl, bsum, off, cursor, n, E);
    scatter_k<<<1024, 256, 0, stream>>>(ei, cursor, csr, E, n);

    // --- GAT layer 1: GEMM -> int8 h1 (+dots), agg -> bf16 hl2 ---
    tgemm_k<128, 128, 32, 0, 2, false, 2><<<gblk, 256, 0, stream>>>(
        x, W1, nullptr, h1q, sc1, as1w, ad1w, as1, ad1, n);
    gat_agg_k<128, 2, 1, true><<<abl, 256, 0, stream>>>(
        csr, off, as1, ad1, h1q, sc1, b1, hl2b, n);

    // --- GAT layer 2: GEMM (bf16 A) -> int8 h2 (+dots), agg -> f32 o_gat ---
    tgemm_k<128, 64, 32, 0, 2, true, 1><<<gblk, 256, 0, stream>>>(
        hl2b, W2, nullptr, h2q, sc2, as2w, ad2w, as2, ad2, n);
    gat_agg_k<64, 1, 0, false><<<abl, 256, 0, stream>>>(
        csr, off, as2, ad2, h2q, sc2, b2, o_gat, n);

    // --- VAE ---
    tgemm_k<64, 128, 32, 1, 0, false, 0><<<gblk, 256, 0, stream>>>(
        o_gat, fc1w, fc1b, h1v, nullptr, nullptr, nullptr, nullptr, nullptr, n);
    mulv_k<<<gblk, 256, 0, stream>>>(h1v, muw, lvw, mub, lvb, eps, o_mu, o_lv, zb, n);
    tgemm_k<16, 128, 16, 1, 0, false, 0><<<gblk, 256, 0, stream>>>(
        zb, fc3w, fc3b, h3, nullptr, nullptr, nullptr, nullptr, nullptr, n);
    tgemm_k<128, 64, 32, 0, 0, false, 0><<<gblk, 256, 0, stream>>>(
        h3, fc4w, fc4b, o_recon, nullptr, nullptr, nullptr, nullptr, nullptr, n);
}

// Round 9
// 423.630 us; speedup vs baseline: 7.0962x; 1.2415x over previous
//
#include <hip/hip_runtime.h>
#include <hip/hip_bf16.h>

typedef __attribute__((ext_vector_type(8))) short bf16x8;
typedef __attribute__((ext_vector_type(4))) float f32x4;

__device__ __forceinline__ unsigned short f2b_bits(float x) {
    __hip_bfloat16 h = __float2bfloat16(x);
    unsigned short u;
    __builtin_memcpy(&u, &h, 2);
    return u;
}
__device__ __forceinline__ unsigned int pack2(float a, float b) {
    return (unsigned int)f2b_bits(a) | ((unsigned int)f2b_bits(b) << 16);
}
__device__ __forceinline__ float sx8(unsigned int w, int b) {   // signed byte b of w
    return (float)((int)(w << (24 - 8 * b)) >> 24);
}

// ================= MFMA node GEMM =================
// D[ch][node] = sum_k W[k][ch] * A[node][k]  (A-operand = weights, B-operand = nodes)
// EPI: 0 = f32 out (+bias,+ACT relu) ; 1 = bf16 out (+bias,+ACT)
//      2 = int8 row-quant out + scales + attention dots (HD heads)
//      3 = mu/lv/z VAE epilogue (FOUT=32: tiles 0=mu,1=lv)
template<int FIN, int FOUT, int EPI, int HD, bool ABF, int ACT>
__global__ __launch_bounds__(256) void mfma_k(const void* __restrict__ Av,
                                              const float* __restrict__ W,
                                              const float* __restrict__ W2,
                                              const float* __restrict__ bias,
                                              const float* __restrict__ bias2,
                                              void* __restrict__ outv,
                                              void* __restrict__ out2,
                                              void* __restrict__ out3,
                                              float* __restrict__ scales,
                                              const float* __restrict__ asr,
                                              const float* __restrict__ adr,
                                              float* __restrict__ aso,
                                              float* __restrict__ ado,
                                              const float* __restrict__ epsp,
                                              int n)
{
    constexpr int KE = (FIN < 32) ? 32 : FIN;   // staged k extent (zero-padded)
    constexpr int KP = KE + 8;                  // row stride in bf16 (bank-spread, 16B mult)
    constexpr int KS = KE / 32;                 // MFMA K-steps
    constexpr int NT = FOUT / 16;               // 16-wide output tiles
    __shared__ __align__(16) unsigned short As[64 * KP];
    __shared__ __align__(16) unsigned short Wt[FOUT * KP];

    const int t  = threadIdx.x;
    const int m0 = blockIdx.x * 64;

    // ---- stage A rows (64 x KE) as bf16, coalesced ----
    for (int idx = t; idx < 64 * (KE / 4); idx += 256) {
        int r  = idx / (KE / 4);
        int c4 = (idx % (KE / 4)) * 4;
        int row = m0 + r;
        unsigned int p0 = 0, p1 = 0;
        if (row < n && c4 < FIN) {
            if constexpr (ABF) {
                uint2 rv = *(const uint2*)((const unsigned short*)Av + (size_t)row * FIN + c4);
                p0 = rv.x; p1 = rv.y;
            } else {
                float4 v = *(const float4*)((const float*)Av + (size_t)row * FIN + c4);
                p0 = pack2(v.x, v.y); p1 = pack2(v.z, v.w);
            }
        }
        *(uint2*)(As + r * KP + c4) = make_uint2(p0, p1);
    }
    // ---- stage W transposed (FOUT x KE) as bf16 ----
    for (int idx = t; idx < KE * (FOUT / 4); idx += 256) {
        int k  = idx / (FOUT / 4);
        int c4 = (idx % (FOUT / 4)) * 4;
        float4 v = make_float4(0.f, 0.f, 0.f, 0.f);
        if (k < FIN) {
            if constexpr (EPI == 3) {
                v = (c4 < 16) ? *(const float4*)(W  + (size_t)k * 16 + c4)
                              : *(const float4*)(W2 + (size_t)k * 16 + (c4 - 16));
            } else {
                v = *(const float4*)(W + (size_t)k * FOUT + c4);
            }
        }
        Wt[(c4 + 0) * KP + k] = f2b_bits(v.x);
        Wt[(c4 + 1) * KP + k] = f2b_bits(v.y);
        Wt[(c4 + 2) * KP + k] = f2b_bits(v.z);
        Wt[(c4 + 3) * KP + k] = f2b_bits(v.w);
    }
    __syncthreads();

    const int w   = t >> 6;          // wave 0..3 -> nodes m0+16w .. +15
    const int l   = t & 63;
    const int l15 = l & 15;          // node within wave / D col
    const int g   = l >> 4;          // k-chunk group / D row group
    const int node = m0 + w * 16 + l15;

    f32x4 acc[NT];
    #pragma unroll
    for (int i = 0; i < NT; ++i) acc[i] = (f32x4){0.f, 0.f, 0.f, 0.f};

    #pragma unroll
    for (int ks = 0; ks < KS; ++ks) {
        bf16x8 nf = *(const bf16x8*)(As + (w * 16 + l15) * KP + ks * 32 + g * 8);
        #pragma unroll
        for (int tt = 0; tt < NT; ++tt) {
            bf16x8 wf = *(const bf16x8*)(Wt + (tt * 16 + l15) * KP + ks * 32 + g * 8);
            acc[tt] = __builtin_amdgcn_mfma_f32_16x16x32_bf16(wf, nf, acc[tt], 0, 0, 0);
        }
    }

    // D layout: lane holds channels {16*tt + 4*g + j} (j=0..3) for its node (=l15 col).
    if constexpr (EPI == 0 || EPI == 1) {
        #pragma unroll
        for (int tt = 0; tt < NT; ++tt) {
            float4 bb = *(const float4*)(bias + 16 * tt + 4 * g);
            float o0 = acc[tt][0] + bb.x, o1 = acc[tt][1] + bb.y;
            float o2 = acc[tt][2] + bb.z, o3 = acc[tt][3] + bb.w;
            if (ACT == 1) {
                o0 = fmaxf(o0, 0.f); o1 = fmaxf(o1, 0.f);
                o2 = fmaxf(o2, 0.f); o3 = fmaxf(o3, 0.f);
            }
            if (node < n) {
                if constexpr (EPI == 0) {
                    *(float4*)((float*)outv + (size_t)node * FOUT + 16 * tt + 4 * g) =
                        make_float4(o0, o1, o2, o3);
                } else {
                    *(uint2*)((unsigned short*)outv + (size_t)node * FOUT + 16 * tt + 4 * g) =
                        make_uint2(pack2(o0, o1), pack2(o2, o3));
                }
            }
        }
    } else if constexpr (EPI == 2) {
        float amax = 0.f;
        float dsh[HD], ddh[HD];
        #pragma unroll
        for (int h = 0; h < HD; ++h) { dsh[h] = 0.f; ddh[h] = 0.f; }
        #pragma unroll
        for (int tt = 0; tt < NT; ++tt) {
            float4 av = *(const float4*)(asr + 16 * tt + 4 * g);
            float4 dv = *(const float4*)(adr + 16 * tt + 4 * g);
            const float* avp = (const float*)&av;
            const float* dvp = (const float*)&dv;
            constexpr int TPH = NT;  // tiles per head handled below
            const int h = (HD == 2) ? (tt / (NT / 2)) : 0;
            #pragma unroll
            for (int j = 0; j < 4; ++j) {
                float xv = acc[tt][j];
                amax = fmaxf(amax, fabsf(xv));
                dsh[h] = fmaf(xv, avp[j], dsh[h]);
                ddh[h] = fmaf(xv, dvp[j], ddh[h]);
            }
            (void)TPH;
        }
        amax = fmaxf(amax, __shfl_xor(amax, 16, 64));
        amax = fmaxf(amax, __shfl_xor(amax, 32, 64));
        #pragma unroll
        for (int h = 0; h < HD; ++h) {
            dsh[h] += __shfl_xor(dsh[h], 16, 64);
            dsh[h] += __shfl_xor(dsh[h], 32, 64);
            ddh[h] += __shfl_xor(ddh[h], 16, 64);
            ddh[h] += __shfl_xor(ddh[h], 32, 64);
        }
        float invsc = amax > 0.f ? 127.f / amax : 0.f;
        if (node < n) {
            #pragma unroll
            for (int tt = 0; tt < NT; ++tt) {
                int q0 = __float2int_rn(acc[tt][0] * invsc);
                int q1 = __float2int_rn(acc[tt][1] * invsc);
                int q2 = __float2int_rn(acc[tt][2] * invsc);
                int q3 = __float2int_rn(acc[tt][3] * invsc);
                unsigned int pv = (q0 & 255) | ((q1 & 255) << 8) |
                                  ((q2 & 255) << 16) | ((q3 & 255) << 24);
                ((unsigned int*)outv)[(size_t)node * (FOUT / 4) + 4 * tt + g] = pv;
            }
            if (g == 0) {
                scales[node] = amax * (1.f / 127.f);
                #pragma unroll
                for (int h = 0; h < HD; ++h) {
                    aso[(size_t)node * HD + h] = dsh[h];
                    ado[(size_t)node * HD + h] = ddh[h];
                }
            }
        }
    } else {   // EPI == 3: mu (tile 0) / logvar (tile 1) / z
        float4 mb = *(const float4*)(bias  + 4 * g);
        float4 lb = *(const float4*)(bias2 + 4 * g);
        float mu0 = acc[0][0] + mb.x, mu1 = acc[0][1] + mb.y;
        float mu2 = acc[0][2] + mb.z, mu3 = acc[0][3] + mb.w;
        float lv0 = acc[1][0] + lb.x, lv1 = acc[1][1] + lb.y;
        float lv2 = acc[1][2] + lb.z, lv3 = acc[1][3] + lb.w;
        if (node < n) {
            float4 ep = *(const float4*)(epsp + (size_t)node * 16 + 4 * g);
            float z0 = fmaf(ep.x, __expf(0.5f * fminf(fmaxf(lv0, -10.f), 10.f)), mu0);
            float z1 = fmaf(ep.y, __expf(0.5f * fminf(fmaxf(lv1, -10.f), 10.f)), mu1);
            float z2 = fmaf(ep.z, __expf(0.5f * fminf(fmaxf(lv2, -10.f), 10.f)), mu2);
            float z3 = fmaf(ep.w, __expf(0.5f * fminf(fmaxf(lv3, -10.f), 10.f)), mu3);
            *(float4*)((float*)outv + (size_t)node * 16 + 4 * g) = make_float4(mu0, mu1, mu2, mu3);
            *(float4*)((float*)out2 + (size_t)node * 16 + 4 * g) = make_float4(lv0, lv1, lv2, lv3);
            *(uint2*)((unsigned short*)out3 + (size_t)node * 16 + 4 * g) =
                make_uint2(pack2(z0, z1), pack2(z2, z3));
        }
    }
}

// ---------------- CSR build ----------------
__global__ __launch_bounds__(256) void count_k(const int* __restrict__ ei, int* __restrict__ deg, int E)
{
    int e = blockIdx.x * 256 + threadIdx.x;
    if (e >= E) return;
    atomicAdd(&deg[ei[E + e]], 1);
}

__global__ __launch_bounds__(256) void scanA_k(const int* __restrict__ deg, int* __restrict__ incl,
                                               int* __restrict__ bsum, int n)
{
    __shared__ int sh[256];
    int i = blockIdx.x * 256 + threadIdx.x;
    int v = (i < n) ? deg[i] : 0;
    sh[threadIdx.x] = v;
    __syncthreads();
    #pragma unroll
    for (int o = 1; o < 256; o <<= 1) {
        int t = (threadIdx.x >= o) ? sh[threadIdx.x - o] : 0;
        __syncthreads();
        sh[threadIdx.x] += t;
        __syncthreads();
    }
    if (i < n) incl[i] = sh[threadIdx.x];
    if (threadIdx.x == 255) bsum[blockIdx.x] = sh[255];
}

__global__ __launch_bounds__(512) void scanB_k(int* __restrict__ bsum, int nb)
{
    __shared__ int sh[512];
    int v = (threadIdx.x < nb) ? bsum[threadIdx.x] : 0;
    sh[threadIdx.x] = v;
    __syncthreads();
    #pragma unroll
    for (int o = 1; o < 512; o <<= 1) {
        int t = (threadIdx.x >= o) ? sh[threadIdx.x - o] : 0;
        __syncthreads();
        sh[threadIdx.x] += t;
        __syncthreads();
    }
    if (threadIdx.x < nb) bsum[threadIdx.x] = sh[threadIdx.x] - v;
}

__global__ __launch_bounds__(256) void scanC_k(const int* __restrict__ deg, const int* __restrict__ incl,
                                               const int* __restrict__ bsum, int* __restrict__ off,
                                               int* __restrict__ cursor, int n, int E)
{
    int i = blockIdx.x * 256 + threadIdx.x;
    if (i >= n) return;
    int v = incl[i] - deg[i] + bsum[i >> 8];
    off[i] = v;
    cursor[i] = v;
    if (i == 0) off[n] = E;
}

// dst-range-partitioned scatter (write-combining within one XCD's L2 per range)
__global__ __launch_bounds__(256) void scatter_k(const int* __restrict__ ei, int* __restrict__ cursor,
                                                 int* __restrict__ csr_src, int E, int n)
{
    const int grp = blockIdx.x & 7;
    const int bin = blockIdx.x >> 3;
    const int bpg = gridDim.x >> 3;
    const int rsz = (n + 7) >> 3;
    const int lo = grp * rsz;
    const int hi = min(n, lo + rsz);
    const int stride = bpg * 256;
    for (int e = bin * 256 + threadIdx.x; e < E; e += stride) {
        int d = ei[E + e];
        if (d >= lo && d < hi) {
            int pos = atomicAdd(&cursor[d], 1);
            csr_src[pos] = ei[e];
        }
    }
}

// ---------------- fused per-dst softmax + aggregate (int8 h, scale folded into alpha) ----------------
template<int FEAT, int H, int ACT, bool OUTB>
__global__ __launch_bounds__(256) void gat_agg_k(const int* __restrict__ csr_src,
                                                 const int* __restrict__ off,
                                                 const float* __restrict__ as_,
                                                 const float* __restrict__ ad_,
                                                 const unsigned int* __restrict__ h8,
                                                 const float* __restrict__ sc,
                                                 const float* __restrict__ bias,
                                                 void* __restrict__ outv, int n)
{
    constexpr int LANES = 16;
    constexpr int FPL   = FEAT / LANES;
    constexpr int WPR   = FEAT / 4;
    constexpr int SUBL  = LANES / H;
    constexpr int NCH   = 4;
    const int tid = blockIdx.x * 256 + threadIdx.x;
    const int d = tid >> 4;
    if (d >= n) return;
    const int lane = threadIdx.x & 15;
    const int myhead = lane / SUBL;
    const int sl = lane % SUBL;
    const int start = off[d], end = off[d + 1];
    const float adm = ad_[d * H + myhead];

    float vreg[NCH], sreg_sc[NCH]; int sreg[NCH];
    float m = -3.4e38f;
    #pragma unroll
    for (int c = 0; c < NCH; ++c) {
        int j = start + sl + c * SUBL;
        int s = 0; float v = -3.4e38f, scl = 0.f;
        if (j < end) {
            s = csr_src[j];
            v = as_[s * H + myhead] + adm;
            v = v > 0.f ? v : 0.2f * v;
            scl = sc[s];
        }
        sreg[c] = s; vreg[c] = v; sreg_sc[c] = scl;
        m = fmaxf(m, v);
    }
    for (int j = start + sl + NCH * SUBL; j < end; j += SUBL) {
        int s = csr_src[j];
        float v = as_[s * H + myhead] + adm;
        v = v > 0.f ? v : 0.2f * v;
        m = fmaxf(m, v);
    }
    #pragma unroll
    for (int o = SUBL / 2; o > 0; o >>= 1)
        m = fmaxf(m, __shfl_xor(m, o, SUBL));

    float ssum = 0.f;
    #pragma unroll
    for (int c = 0; c < NCH; ++c)
        if (start + sl + c * SUBL < end) ssum += __expf(vreg[c] - m);
    for (int j = start + sl + NCH * SUBL; j < end; j += SUBL) {
        int s = csr_src[j];
        float v = as_[s * H + myhead] + adm;
        v = v > 0.f ? v : 0.2f * v;
        ssum += __expf(v - m);
    }
    #pragma unroll
    for (int o = SUBL / 2; o > 0; o >>= 1)
        ssum += __shfl_xor(ssum, o, SUBL);
    const float inv = 1.f / (ssum + 1e-16f);

    float acc[FPL];
    #pragma unroll
    for (int k = 0; k < FPL; ++k) acc[k] = 0.f;

    auto body = [&](float a, int s) {
        if constexpr (FPL == 8) {
            uint2 r = ((const uint2*)(h8 + (size_t)s * WPR))[lane];
            acc[0] = fmaf(sx8(r.x, 0), a, acc[0]);
            acc[1] = fmaf(sx8(r.x, 1), a, acc[1]);
            acc[2] = fmaf(sx8(r.x, 2), a, acc[2]);
            acc[3] = fmaf(sx8(r.x, 3), a, acc[3]);
            acc[4] = fmaf(sx8(r.y, 0), a, acc[4]);
            acc[5] = fmaf(sx8(r.y, 1), a, acc[5]);
            acc[6] = fmaf(sx8(r.y, 2), a, acc[6]);
            acc[7] = fmaf(sx8(r.y, 3), a, acc[7]);
        } else {
            unsigned int r = (h8 + (size_t)s * WPR)[lane];
            acc[0] = fmaf(sx8(r, 0), a, acc[0]);
            acc[1] = fmaf(sx8(r, 1), a, acc[1]);
            acc[2] = fmaf(sx8(r, 2), a, acc[2]);
            acc[3] = fmaf(sx8(r, 3), a, acc[3]);
        }
    };

    const int nch = (end - start + SUBL - 1) / SUBL;
    for (int c = 0; c < nch; ++c) {
        const int j0 = start + c * SUBL;
        const int cnt = min(SUBL, end - j0);
        float myalpha = 0.f; int mysrc = 0;
        if (c < NCH) {
            mysrc = sreg[c];
            if (sl < cnt) myalpha = __expf(vreg[c] - m) * inv * sreg_sc[c];
        } else {
            if (sl < cnt) {
                mysrc = csr_src[j0 + sl];
                float v = as_[mysrc * H + myhead] + adm;
                v = v > 0.f ? v : 0.2f * v;
                myalpha = __expf(v - m) * inv * sc[mysrc];
            }
        }
        if (cnt == SUBL) {
            #pragma unroll
            for (int u = 0; u < SUBL; ++u) {
                float a = __shfl(myalpha, myhead * SUBL + u, LANES);
                int   s = __shfl(mysrc, u, LANES);
                body(a, s);
            }
        } else {
            for (int u = 0; u < cnt; ++u) {
                float a = __shfl(myalpha, myhead * SUBL + u, LANES);
                int   s = __shfl(mysrc, u, LANES);
                body(a, s);
            }
        }
    }

    if constexpr (OUTB) {
        float o[FPL];
        #pragma unroll
        for (int k = 0; k < FPL; ++k) {
            o[k] = acc[k] + bias[lane * FPL + k];
            if (ACT == 1) o[k] = fmaxf(o[k], 0.f);
        }
        uint4 pv;
        pv.x = pack2(o[0], o[1]); pv.y = pack2(o[2], o[3]);
        pv.z = pack2(o[4], o[5]); pv.w = pack2(o[6], o[7]);
        *(uint4*)((unsigned short*)outv + (size_t)d * FEAT + lane * FPL) = pv;
    } else {
        float* outf = (float*)outv;
        #pragma unroll
        for (int k = 0; k < FPL; ++k) {
            float o = acc[k] + bias[lane * FPL + k];
            if (ACT == 1) o = fmaxf(o, 0.f);
            outf[(size_t)d * FEAT + lane * FPL + k] = o;
        }
    }
}

// ---------------- launch ----------------
extern "C" void kernel_launch(void* const* d_in, const int* in_sizes, int n_in,
                              void* d_out, int out_size, void* d_ws, size_t ws_size,
                              hipStream_t stream)
{
    const int n = in_sizes[0] / 128;     // N nodes
    const int E = in_sizes[1] / 2;       // edges

    const float* x   = (const float*)d_in[0];
    const int*   ei  = (const int*)d_in[1];
    const float* eps = (const float*)d_in[3];
    const float* W1  = (const float*)d_in[4];
    const float* as1w= (const float*)d_in[5];
    const float* ad1w= (const float*)d_in[6];
    const float* b1  = (const float*)d_in[7];
    const float* W2  = (const float*)d_in[8];
    const float* as2w= (const float*)d_in[9];
    const float* ad2w= (const float*)d_in[10];
    const float* b2  = (const float*)d_in[11];
    const float* fc1w= (const float*)d_in[12];
    const float* fc1b= (const float*)d_in[13];
    const float* muw = (const float*)d_in[14];
    const float* mub = (const float*)d_in[15];
    const float* lvw = (const float*)d_in[16];
    const float* lvb = (const float*)d_in[17];
    const float* fc3w= (const float*)d_in[18];
    const float* fc3b= (const float*)d_in[19];
    const float* fc4w= (const float*)d_in[20];
    const float* fc4b= (const float*)d_in[21];

    char* ws = (char*)d_ws;

    size_t oDeg   = 0;
    size_t oOff   = oDeg  + (size_t)n * 4;
    size_t oIncl  = oOff  + (size_t)(n + 1) * 4;
    size_t oCur   = oIncl + (size_t)n * 4;
    size_t oBsum  = oCur  + (size_t)n * 4;
    size_t oCsr   = oBsum + 512 * 4;
    size_t oR1    = oCsr  + (size_t)E * 4;          // h1q int8[n,128] -> h1v bf16[n,128]
    size_t oR2    = oR1   + (size_t)n * 256;        // hl2b bf16[n,128] -> h3 bf16[n,128]
    size_t oR3    = oR2   + (size_t)n * 256;        // h2q int8[n,64] -> zb bf16[n,16]
    size_t oAS1   = oR3   + (size_t)n * 128;
    size_t oAD1   = oAS1  + (size_t)n * 2 * 4;
    size_t oAS2   = oAD1  + (size_t)n * 2 * 4;
    size_t oAD2   = oAS2  + (size_t)n * 4;
    size_t oSC1   = oAD2  + (size_t)n * 4;
    size_t oSC2   = oSC1  + (size_t)n * 4;

    int* deg    = (int*)(ws + oDeg);
    int* off    = (int*)(ws + oOff);
    int* incl   = (int*)(ws + oIncl);
    int* cursor = (int*)(ws + oCur);
    int* bsum   = (int*)(ws + oBsum);
    int* csr    = (int*)(ws + oCsr);
    unsigned int*   h1q  = (unsigned int*)(ws + oR1);
    unsigned short* h1v  = (unsigned short*)(ws + oR1);   // reuse after h1q dead
    unsigned short* hl2b = (unsigned short*)(ws + oR2);
    unsigned short* h3   = (unsigned short*)(ws + oR2);   // reuse after hl2b dead
    unsigned int*   h2q  = (unsigned int*)(ws + oR3);
    unsigned short* zb   = (unsigned short*)(ws + oR3);   // reuse after h2q dead
    float* as1  = (float*)(ws + oAS1);
    float* ad1  = (float*)(ws + oAD1);
    float* as2  = (float*)(ws + oAS2);
    float* ad2  = (float*)(ws + oAD2);
    float* sc1  = (float*)(ws + oSC1);
    float* sc2  = (float*)(ws + oSC2);

    float* out     = (float*)d_out;
    float* o_recon = out;
    float* o_mu    = out + (size_t)n * 64;
    float* o_lv    = out + (size_t)n * 80;
    float* o_gat   = out + (size_t)n * 96;

    const int ebl  = (E + 255) / 256;
    const int nbS  = (n + 255) / 256;
    const int abl  = (n * 16 + 255) / 256;
    const int g64  = (n + 63) / 64;

    // --- CSR build ---
    hipMemsetAsync(deg, 0, (size_t)n * 4, stream);
    count_k<<<ebl, 256, 0, stream>>>(ei, deg, E);
    scanA_k<<<nbS, 256, 0, stream>>>(deg, incl, bsum, n);
    scanB_k<<<1, 512, 0, stream>>>(bsum, nbS);
    scanC_k<<<nbS, 256, 0, stream>>>(deg, incl, bsum, off, cursor, n, E);
    scatter_k<<<1024, 256, 0, stream>>>(ei, cursor, csr, E, n);

    // --- GAT layer 1: MFMA GEMM -> int8 h1 (+dots+scales), agg -> bf16 hl2 ---
    mfma_k<128, 128, 2, 2, false, 0><<<g64, 256, 0, stream>>>(
        x, W1, nullptr, nullptr, nullptr, h1q, nullptr, nullptr,
        sc1, as1w, ad1w, as1, ad1, nullptr, n);
    gat_agg_k<128, 2, 1, true><<<abl, 256, 0, stream>>>(
        csr, off, as1, ad1, h1q, sc1, b1, hl2b, n);

    // --- GAT layer 2: MFMA GEMM (bf16 A) -> int8 h2 (+dots), agg -> f32 o_gat ---
    mfma_k<128, 64, 2, 1, true, 0><<<g64, 256, 0, stream>>>(
        hl2b, W2, nullptr, nullptr, nullptr, h2q, nullptr, nullptr,
        sc2, as2w, ad2w, as2, ad2, nullptr, n);
    gat_agg_k<64, 1, 0, false><<<abl, 256, 0, stream>>>(
        csr, off, as2, ad2, h2q, sc2, b2, o_gat, n);

    // --- VAE ---
    mfma_k<64, 128, 1, 0, false, 1><<<g64, 256, 0, stream>>>(          // fc1 + relu -> bf16 h1v
        o_gat, fc1w, nullptr, fc1b, nullptr, h1v, nullptr, nullptr,
        nullptr, nullptr, nullptr, nullptr, nullptr, nullptr, n);
    mfma_k<128, 32, 3, 0, true, 0><<<g64, 256, 0, stream>>>(           // mu/lv/z fused
        h1v, muw, lvw, mub, lvb, o_mu, o_lv, zb,
        nullptr, nullptr, nullptr, nullptr, nullptr, eps, n);
    mfma_k<16, 128, 1, 0, true, 1><<<g64, 256, 0, stream>>>(           // fc3 + relu -> bf16 h3
        zb, fc3w, nullptr, fc3b, nullptr, h3, nullptr, nullptr,
        nullptr, nullptr, nullptr, nullptr, nullptr, nullptr, n);
    mfma_k<128, 64, 0, 0, true, 0><<<g64, 256, 0, stream>>>(           // fc4 -> f32 recon
        h3, fc4w, nullptr, fc4b, nullptr, o_recon, nullptr, nullptr,
        nullptr, nullptr, nullptr, nullptr, nullptr, nullptr, n);
}